// Round 2
// baseline (1602.876 us; speedup 1.0000x reference)
//
#include <hip/hip_runtime.h>
#include <math.h>

#define NN 50000
#define EA 800000
#define EC 400000
#define EIN 600000
#define NG 128
#define FIN 54

#define DEV_VDW 0.2f
#define EPS_LO_ 0.0178f
#define EPS_HI_ 0.2f

__device__ __forceinline__ float wsum(float v){
  #pragma unroll
  for (int o = 32; o; o >>= 1) v += __shfl_xor(v, o, 64);
  return v;
}

// ---------------- CSR build ----------------
__global__ void k_count(const int* __restrict__ dst, int E, int* __restrict__ cnt){
  int i = blockIdx.x * blockDim.x + threadIdx.x;
  int stride = gridDim.x * blockDim.x;
  for (; i < E; i += stride) atomicAdd(&cnt[dst[i]], 1);
}

__global__ void k_scan(const int* __restrict__ cnt, int n, int* __restrict__ off, int* __restrict__ cur){
  __shared__ int wsums[16];
  __shared__ int run_s;
  int tid = threadIdx.x;            // 1024
  int lane = tid & 63, w = tid >> 6;
  if (tid == 0) run_s = 0;
  __syncthreads();
  for (int base = 0; base < n; base += 1024){
    int run = run_s;
    int i = base + tid;
    int v = (i < n) ? cnt[i] : 0;
    int s = v;
    #pragma unroll
    for (int o = 1; o < 64; o <<= 1){ int t = __shfl_up(s, o, 64); if (lane >= o) s += t; }
    if (lane == 63) wsums[w] = s;
    __syncthreads();
    if (w == 0 && lane < 16){
      int t = wsums[lane];
      #pragma unroll
      for (int o = 1; o < 16; o <<= 1){ int u = __shfl_up(t, o, 64); if (lane >= o) t += u; }
      wsums[lane] = t;
    }
    __syncthreads();
    int woff = (w == 0) ? 0 : wsums[w - 1];
    int excl = run + woff + (s - v);
    if (i < n){ off[i] = excl; cur[i] = excl; }
    int tot = wsums[15];
    __syncthreads();
    if (tid == 0) run_s = run + tot;
    __syncthreads();
  }
  if (threadIdx.x == 0) off[n] = run_s;
}

__global__ void k_place(const int* __restrict__ src, const int* __restrict__ dst, int E,
                        int* __restrict__ cur, int* __restrict__ out_src){
  int i = blockIdx.x * blockDim.x + threadIdx.x;
  int stride = gridDim.x * blockDim.x;
  for (; i < E; i += stride){
    int d = dst[i];
    int slot = atomicAdd(&cur[d], 1);
    out_src[slot] = src[i];
  }
}

// ---------------- embed: H = X[NN,54] @ W[54,128] ----------------
__global__ void k_embed(const float* __restrict__ X, const float* __restrict__ W, float* __restrict__ H){
  __shared__ float Wls[FIN * 128];
  int tid = threadIdx.x; // 128
  for (int i = tid; i < FIN * 128; i += 128) Wls[i] = W[i];
  __syncthreads();
  for (int row = blockIdx.x; row < NN; row += gridDim.x){
    const float* xr = X + row * FIN;
    float acc = 0.f;
    #pragma unroll
    for (int k = 0; k < FIN; ++k) acc += xr[k] * Wls[k * 128 + tid];
    H[(size_t)row * 128 + tid] = acc;
  }
}

// ---------------- GEMM: C[N,128] = A[N,128] @ B[128,128] (+bias)(+relu) ----------------
template<bool BIAS, bool RELU>
__global__ __launch_bounds__(256) void k_gemm(const float* __restrict__ A, const float* __restrict__ B,
                                              const float* __restrict__ bias, float* __restrict__ C, int N){
  __shared__ float Als[64 * 132];   // 64 rows, stride 132 (pad kills bank conflicts)
  int tid = threadIdx.x;
  int row0 = blockIdx.x * 64;
  {
    int r = tid >> 5;       // 0..7
    int kq = tid & 31;      // float4 index along k
    #pragma unroll
    for (int it = 0; it < 8; ++it){
      int rr = r + it * 8;
      int row = row0 + rr;
      float4 v = make_float4(0.f, 0.f, 0.f, 0.f);
      if (row < N) v = *(const float4*)(A + (size_t)row * 128 + kq * 4);
      *(float4*)&Als[rr * 132 + kq * 4] = v;
    }
  }
  __syncthreads();
  int ct = tid & 15;
  int rt = tid >> 4;        // 0..15
  int c0 = ct * 4;
  float acc[4][8] = {};
  for (int k0 = 0; k0 < 128; k0 += 4){
    float a_[4][4];
    #pragma unroll
    for (int u = 0; u < 4; ++u){
      float4 av = *(const float4*)&Als[(rt * 4 + u) * 132 + k0];
      a_[u][0] = av.x; a_[u][1] = av.y; a_[u][2] = av.z; a_[u][3] = av.w;
    }
    #pragma unroll
    for (int kk = 0; kk < 4; ++kk){
      const float* Bk = B + (k0 + kk) * 128;
      float4 b0 = *(const float4*)(Bk + c0);
      float4 b1 = *(const float4*)(Bk + 64 + c0);
      float bb[8] = {b0.x, b0.y, b0.z, b0.w, b1.x, b1.y, b1.z, b1.w};
      #pragma unroll
      for (int u = 0; u < 4; ++u){
        float av = a_[u][kk];
        #pragma unroll
        for (int v = 0; v < 8; ++v) acc[u][v] += av * bb[v];
      }
    }
  }
  float bv[8];
  if (BIAS){
    float4 t0 = *(const float4*)(bias + c0);
    float4 t1 = *(const float4*)(bias + 64 + c0);
    bv[0] = t0.x; bv[1] = t0.y; bv[2] = t0.z; bv[3] = t0.w;
    bv[4] = t1.x; bv[5] = t1.y; bv[6] = t1.z; bv[7] = t1.w;
  } else {
    #pragma unroll
    for (int v = 0; v < 8; ++v) bv[v] = 0.f;
  }
  #pragma unroll
  for (int u = 0; u < 4; ++u){
    int row = row0 + rt * 4 + u;
    if (row < N){
      float o[8];
      #pragma unroll
      for (int v = 0; v < 8; ++v){
        float t = acc[u][v] + bv[v];
        if (RELU) t = fmaxf(t, 0.f);
        o[v] = t;
      }
      *(float4*)(C + (size_t)row * 128 + c0)      = make_float4(o[0], o[1], o[2], o[3]);
      *(float4*)(C + (size_t)row * 128 + 64 + c0) = make_float4(o[4], o[5], o[6], o[7]);
    }
  }
}

// ---------------- GAT layer (one wave per node, online softmax) ----------------
__global__ void k_gat(float* __restrict__ H, const float* __restrict__ HW, const float* __restrict__ HA,
                      const int* __restrict__ off, const int* __restrict__ srcs,
                      const float* __restrict__ GW, const float* __restrict__ GB){
  int n = blockIdx.x * 4 + (threadIdx.x >> 6);
  if (n >= NN) return;
  int lane = threadIdx.x & 63;
  const float* han = HA + (size_t)n * 128;
  float a0 = han[lane], a1 = han[64 + lane];
  int e0 = off[n], e1 = off[n + 1];
  float m = -INFINITY, den = 0.f, acc0 = 0.f, acc1 = 0.f;
  for (int e = e0; e < e1; ++e){
    int s = srcs[e];
    const float* hs = HW + (size_t)s * 128;
    float w0 = hs[lane], w1 = hs[64 + lane];
    float p = wsum(a0 * w0 + a1 * w1);
    float mn = fmaxf(m, p);
    float cf = __expf(m - mn);   // exp(-inf)=0 on first edge
    float ex = __expf(p - mn);
    den  = den  * cf + ex;
    acc0 = acc0 * cf + ex * w0;
    acc1 = acc1 * cf + ex * w1;
    m = mn;
  }
  float inv = 1.f / (den + 1e-16f);
  float hp0 = fmaxf(acc0 * inv, 0.f), hp1 = fmaxf(acc1 * inv, 0.f);
  float x0 = H[(size_t)n * 128 + lane], x1 = H[(size_t)n * 128 + 64 + lane];
  float g = wsum(x0 * GW[lane] + x1 * GW[64 + lane] + hp0 * GW[128 + lane] + hp1 * GW[192 + lane]) + GB[0];
  float z = 1.f / (1.f + __expf(-g));
  H[(size_t)n * 128 + lane]      = z * x0 + (1.f - z) * hp0;
  H[(size_t)n * 128 + 64 + lane] = z * x1 + (1.f - z) * hp1;
}

// ---------------- interaction layer ----------------
__global__ void k_inter(float* __restrict__ H, const float* __restrict__ T,
                        const int* __restrict__ off, const int* __restrict__ srcs,
                        const float* __restrict__ GW, const float* __restrict__ GB){
  int n = blockIdx.x * 4 + (threadIdx.x >> 6);
  if (n >= NN) return;
  int lane = threadIdx.x & 63;
  int e0 = off[n], e1 = off[n + 1];
  float m0 = 0.f, m1 = 0.f;
  for (int e = e0; e < e1; ++e){
    int s = srcs[e];
    m0 += T[(size_t)s * 128 + lane];
    m1 += T[(size_t)s * 128 + 64 + lane];
  }
  float x0 = H[(size_t)n * 128 + lane], x1 = H[(size_t)n * 128 + 64 + lane];
  float g = wsum(x0 * GW[lane] + x1 * GW[64 + lane] + m0 * GW[128 + lane] + m1 * GW[192 + lane]) + GB[0];
  float z = 1.f / (1.f + __expf(-g));
  H[(size_t)n * 128 + lane]      = z * x0 + (1.f - z) * m0;
  H[(size_t)n * 128 + 64 + lane] = z * x1 + (1.f - z) * m1;
}

// ---------------- final inter-graph edges ----------------
__global__ __launch_bounds__(256) void k_edges(
    const int* __restrict__ EIdx,
    const float* __restrict__ POS, const float* __restrict__ RAD,
    const int* __restrict__ Mmet, const int* __restrict__ Mdon,
    const int* __restrict__ Macc, const int* __restrict__ Mhyd,
    const int* __restrict__ BATCH,
    const float* __restrict__ Pd, const float* __restrict__ Qd,
    const float* __restrict__ Pe, const float* __restrict__ Qe,
    const float* __restrict__ w2d, const float* __restrict__ b2d,
    const float* __restrict__ w2e, const float* __restrict__ b2e,
    const float* __restrict__ hbc, const float* __restrict__ hpc,
    float* __restrict__ geng, float* __restrict__ outdv){
  __shared__ float eg[NG * 4];
  int tid = threadIdx.x;
  for (int i = tid; i < NG * 4; i += 256) eg[i] = 0.f;
  __syncthreads();
  int lane = tid & 63;
  int wid = blockIdx.x * 4 + (tid >> 6);
  int nw = gridDim.x * 4;
  float w2d0 = w2d[lane], w2d1 = w2d[64 + lane];
  float w2e0 = w2e[lane], w2e1 = w2e[64 + lane];
  float bd = b2d[0], be = b2e[0];
  float minhb = -hbc[0] * hbc[0], minhp = -hpc[0] * hpc[0];
  for (int e = wid; e < EIN; e += nw){
    int i = EIdx[e], j = EIdx[EIN + e];
    size_t io = (size_t)i * 128, jo = (size_t)j * 128;
    float hd0 = fmaxf(Pd[io + lane] + Qd[jo + lane], 0.f);
    float hd1 = fmaxf(Pd[io + 64 + lane] + Qd[jo + 64 + lane], 0.f);
    float sd = wsum(hd0 * w2d0 + hd1 * w2d1) + bd;
    float he0 = fmaxf(Pe[io + lane] + Qe[jo + lane], 0.f);
    float he1 = fmaxf(Pe[io + 64 + lane] + Qe[jo + 64 + lane], 0.f);
    float se = wsum(he0 * w2e0 + he1 * w2e1) + be;
    float dx = POS[i * 3 + 0] - POS[j * 3 + 0];
    float dy = POS[i * 3 + 1] - POS[j * 3 + 1];
    float dz = POS[i * 3 + 2] - POS[j * 3 + 2];
    float D = sqrtf(dx * dx + dy * dy + dz * dz + 1e-10f);
    float rmask = (D >= 0.5f && D <= 5.0f) ? 1.f : 0.f;
    float dvdw = tanhf(sd) * DEV_VDW * rmask;
    float eps = (1.f / (1.f + __expf(-se))) * (EPS_HI_ - EPS_LO_) + EPS_LO_;
    if (lane == 0) outdv[e] = dvdw;
    float R = RAD[i] + RAD[j] + dvdw;
    float dr = fmaxf(D / R, 0.5f);
    float nn2 = (dr < 1.f) ? 10.f : 6.f;
    float tp = __expf(-nn2 * __logf(dr));
    float ev = eps * (tp * tp - 2.f * tp);
    float dmr = D - R;
    float f1 = fminf(fmaxf(dmr * (-1.f / 0.7f), 0.f), 1.f);   // ((D-R)-0)/(-0.7-0)
    float f3 = fminf(fmaxf(1.5f - dmr, 0.f), 1.f);            // ((D-R)-1.5)/(0.5-1.5)
    float e1v = minhb * f1;
    float e3v = minhp * f3;
    bool mi = Mmet[i] != 0, mj = Mmet[j] != 0;
    bool ai = Macc[i] != 0, aj = Macc[j] != 0;
    bool di = Mdon[i] != 0, dj = Mdon[j] != 0;
    bool yi = Mhyd[i] != 0, yj = Mhyd[j] != 0;
    bool nm = !(mi || mj);
    float M0 = nm ? 1.f : 0.f;
    float M1 = (((di && aj) || (ai && dj)) && nm) ? 1.f : 0.f;
    float M2 = ((mi && aj) || (ai && mj)) ? 1.f : 0.f;
    float M3 = (yi && yj && nm) ? 1.f : 0.f;
    if (lane == 0){
      int g = BATCH[i] * 4;
      atomicAdd(&eg[g + 0], ev  * M0 * rmask);
      atomicAdd(&eg[g + 1], e1v * M1 * rmask);
      atomicAdd(&eg[g + 2], e1v * M2 * rmask);
      atomicAdd(&eg[g + 3], e3v * M3 * rmask);
    }
  }
  __syncthreads();
  for (int i2 = tid; i2 < NG * 4; i2 += 256) atomicAdd(&geng[i2], eg[i2]);
}

__global__ void k_final(const float* __restrict__ geng, const float* __restrict__ rotor,
                        const float* __restrict__ rc, float* __restrict__ out){
  int t = blockIdx.x * blockDim.x + threadIdx.x;
  if (t < NG * 4){
    int g = t >> 2;
    float pen = 1.f + rc[0] * rc[0] * rotor[g];
    out[t] = geng[t] / pen;
  }
}

extern "C" void kernel_launch(void* const* d_in, const int* in_sizes, int n_in,
                              void* d_out, int out_size, void* d_ws, size_t ws_size,
                              hipStream_t stream){
  (void)in_sizes; (void)n_in; (void)out_size; (void)ws_size;
  const float* X    = (const float*)d_in[0];
  const float* POS  = (const float*)d_in[1];
  const float* RAD  = (const float*)d_in[2];
  const float* ROT  = (const float*)d_in[3];
  const int* EIa    = (const int*)d_in[4];
  const int* EIc    = (const int*)d_in[5];
  const int* EIi    = (const int*)d_in[6];
  const int* BATCH  = (const int*)d_in[7];
  const int* Mmet = (const int*)d_in[8];
  const int* Mdon = (const int*)d_in[9];
  const int* Macc = (const int*)d_in[10];
  const int* Mhyd = (const int*)d_in[11];
  const float* embW  = (const float*)d_in[12];
  const float* gatW  = (const float*)d_in[13];
  const float* gatWb = (const float*)d_in[14];
  const float* gatA  = (const float*)d_in[15];
  const float* gatGw = (const float*)d_in[16];
  const float* gatGb = (const float*)d_in[17];
  const float* intW  = (const float*)d_in[18];
  const float* intWb = (const float*)d_in[19];
  const float* intGw = (const float*)d_in[20];
  const float* intGb = (const float*)d_in[21];
  const float* ew1 = (const float*)d_in[22];
  const float* eb1 = (const float*)d_in[23];
  const float* ew2 = (const float*)d_in[24];
  const float* eb2 = (const float*)d_in[25];
  const float* dw1 = (const float*)d_in[26];
  const float* db1 = (const float*)d_in[27];
  const float* dw2 = (const float*)d_in[28];
  const float* db2 = (const float*)d_in[29];
  const float* hbc = (const float*)d_in[30];
  const float* hpc = (const float*)d_in[31];
  const float* rcc = (const float*)d_in[32];
  float* out = (float*)d_out;

  char* w = (char*)d_ws;
  float* H  = (float*)w; w += (size_t)NN * 128 * 4;
  float* BA = (float*)w; w += (size_t)NN * 128 * 4;
  float* BB = (float*)w; w += (size_t)NN * 128 * 4;
  float* BC = (float*)w; w += (size_t)NN * 128 * 4;
  float* BD = (float*)w; w += (size_t)NN * 128 * 4;
  float* GENG = (float*)w; w += 512 * 4;
  int* cntA = (int*)w; w += (size_t)NN * 4;
  int* offA = (int*)w; w += (size_t)(NN + 1) * 4;
  int* curA = (int*)w; w += (size_t)NN * 4;
  int* srcA = (int*)w; w += (size_t)EA * 4;
  int* cntC = (int*)w; w += (size_t)NN * 4;
  int* offC = (int*)w; w += (size_t)(NN + 1) * 4;
  int* curC = (int*)w; w += (size_t)NN * 4;
  int* srcC = (int*)w; w += (size_t)EC * 4;

  hipMemsetAsync(cntA, 0, (size_t)NN * 4, stream);
  hipMemsetAsync(cntC, 0, (size_t)NN * 4, stream);
  hipMemsetAsync(GENG, 0, 512 * 4, stream);

  k_count<<<1024, 256, 0, stream>>>(EIa + EA, EA, cntA);
  k_scan<<<1, 1024, 0, stream>>>(cntA, NN, offA, curA);
  k_place<<<1024, 256, 0, stream>>>(EIa, EIa + EA, EA, curA, srcA);
  k_count<<<1024, 256, 0, stream>>>(EIc + EC, EC, cntC);
  k_scan<<<1, 1024, 0, stream>>>(cntC, NN, offC, curC);
  k_place<<<1024, 256, 0, stream>>>(EIc, EIc + EC, EC, curC, srcC);

  k_embed<<<2048, 128, 0, stream>>>(X, embW, H);

  int gemmGrid = (NN + 63) / 64;
  for (int l = 0; l < 3; ++l){
    k_gemm<true,  false><<<gemmGrid, 256, 0, stream>>>(H,  gatW + l * 16384, gatWb + l * 128, BA, NN);
    k_gemm<false, false><<<gemmGrid, 256, 0, stream>>>(BA, gatA + l * 16384, nullptr,         BB, NN);
    k_gat<<<(NN + 3) / 4, 256, 0, stream>>>(H, BA, BB, offA, srcA, gatGw + l * 256, gatGb + l);
  }
  for (int l = 0; l < 3; ++l){
    k_gemm<true, true><<<gemmGrid, 256, 0, stream>>>(H, intW + l * 16384, intWb + l * 128, BA, NN);
    k_inter<<<(NN + 3) / 4, 256, 0, stream>>>(H, BA, offC, srcC, intGw + l * 256, intGb + l);
  }
  k_gemm<true,  false><<<gemmGrid, 256, 0, stream>>>(H, dw1,         db1,     BA, NN); // Pd (+b1)
  k_gemm<false, false><<<gemmGrid, 256, 0, stream>>>(H, dw1 + 16384, nullptr, BB, NN); // Qd
  k_gemm<true,  false><<<gemmGrid, 256, 0, stream>>>(H, ew1,         eb1,     BC, NN); // Pe (+b1)
  k_gemm<false, false><<<gemmGrid, 256, 0, stream>>>(H, ew1 + 16384, nullptr, BD, NN); // Qe

  k_edges<<<1024, 256, 0, stream>>>(EIi, POS, RAD, Mmet, Mdon, Macc, Mhyd, BATCH,
                                    BA, BB, BC, BD, dw2, db2, ew2, eb2, hbc, hpc,
                                    GENG, out + 512);
  k_final<<<2, 256, 0, stream>>>(GENG, ROT, rcc, out);
}

// Round 3
// 1359.621 us; speedup vs baseline: 1.1789x; 1.1789x over previous
//
#include <hip/hip_runtime.h>
#include <math.h>

#define NN 50000
#define EA 800000
#define EC 400000
#define EIN 600000
#define NG 128
#define FIN 54

#define DEV_VDW 0.2f
#define EPS_LO_ 0.0178f
#define EPS_HI_ 0.2f

typedef unsigned int uint;
typedef unsigned short ushort;

__device__ __forceinline__ float wsum(float v){
  #pragma unroll
  for (int o = 32; o; o >>= 1) v += __shfl_xor(v, o, 64);
  return v;
}

__device__ __forceinline__ ushort f2bf(float f){
  uint x = __float_as_uint(f);
  uint r = x + 0x7fffu + ((x >> 16) & 1u);
  return (ushort)(r >> 16);
}
__device__ __forceinline__ uint f2bf2(float a, float b){
  return (uint)f2bf(a) | ((uint)f2bf(b) << 16);
}
__device__ __forceinline__ float2 bf2x2(uint u){
  return make_float2(__uint_as_float(u << 16), __uint_as_float(u & 0xffff0000u));
}

// ---------------- CSR build ----------------
__global__ void k_count(const int* __restrict__ dst, int E, int* __restrict__ cnt){
  int i = blockIdx.x * blockDim.x + threadIdx.x;
  int stride = gridDim.x * blockDim.x;
  for (; i < E; i += stride) atomicAdd(&cnt[dst[i]], 1);
}

__global__ void k_scan(const int* __restrict__ cnt, int n, int* __restrict__ off, int* __restrict__ cur){
  __shared__ int wsums[16];
  __shared__ int run_s;
  int tid = threadIdx.x;            // 1024
  int lane = tid & 63, w = tid >> 6;
  if (tid == 0) run_s = 0;
  __syncthreads();
  for (int base = 0; base < n; base += 1024){
    int run = run_s;
    int i = base + tid;
    int v = (i < n) ? cnt[i] : 0;
    int s = v;
    #pragma unroll
    for (int o = 1; o < 64; o <<= 1){ int t = __shfl_up(s, o, 64); if (lane >= o) s += t; }
    if (lane == 63) wsums[w] = s;
    __syncthreads();
    if (w == 0 && lane < 16){
      int t = wsums[lane];
      #pragma unroll
      for (int o = 1; o < 16; o <<= 1){ int u = __shfl_up(t, o, 64); if (lane >= o) t += u; }
      wsums[lane] = t;
    }
    __syncthreads();
    int woff = (w == 0) ? 0 : wsums[w - 1];
    int excl = run + woff + (s - v);
    if (i < n){ off[i] = excl; cur[i] = excl; }
    int tot = wsums[15];
    __syncthreads();
    if (tid == 0) run_s = run + tot;
    __syncthreads();
  }
  if (threadIdx.x == 0) off[n] = run_s;
}

__global__ void k_place(const int* __restrict__ src, const int* __restrict__ dst, int E,
                        int* __restrict__ cur, int* __restrict__ out_src){
  int i = blockIdx.x * blockDim.x + threadIdx.x;
  int stride = gridDim.x * blockDim.x;
  for (; i < E; i += stride){
    int d = dst[i];
    int slot = atomicAdd(&cur[d], 1);
    out_src[slot] = src[i];
  }
}

// ---------------- node static info ----------------
__global__ void k_nodeinfo(const float* __restrict__ POS, const float* __restrict__ RAD,
                           const int* __restrict__ Mmet, const int* __restrict__ Mdon,
                           const int* __restrict__ Macc, const int* __restrict__ Mhyd,
                           const int* __restrict__ BATCH,
                           float4* __restrict__ PRAD, uint* __restrict__ MB){
  int n = blockIdx.x * 256 + threadIdx.x;
  if (n < NN){
    PRAD[n] = make_float4(POS[3*n], POS[3*n+1], POS[3*n+2], RAD[n]);
    uint m = (Mmet[n] ? 1u : 0u) | (Mdon[n] ? 2u : 0u) | (Macc[n] ? 4u : 0u) |
             (Mhyd[n] ? 8u : 0u) | ((uint)BATCH[n] << 8);
    MB[n] = m;
  }
}

// ---------------- embed: H = X[NN,54] @ W[54,128] ----------------
__global__ void k_embed(const float* __restrict__ X, const float* __restrict__ W, float* __restrict__ H){
  __shared__ float Wls[FIN * 128];
  int tid = threadIdx.x; // 128
  for (int i = tid; i < FIN * 128; i += 128) Wls[i] = W[i];
  __syncthreads();
  for (int row = blockIdx.x; row < NN; row += gridDim.x){
    const float* xr = X + row * FIN;
    float acc = 0.f;
    #pragma unroll
    for (int k = 0; k < FIN; ++k) acc += xr[k] * Wls[k * 128 + tid];
    H[(size_t)row * 128 + tid] = acc;
  }
}

// ---------------- GEMM: C16[N,128](bf16) = act(A[N,128] @ B[128,128] + bias) ----------------
template<bool BIAS, bool RELU, bool INBF>
__global__ __launch_bounds__(256) void k_gemm(const void* __restrict__ Av, const float* __restrict__ B,
                                              const float* __restrict__ bias, uint* __restrict__ C16, int N){
  __shared__ float Als[64 * 132];
  int tid = threadIdx.x;
  int row0 = blockIdx.x * 64;
  {
    int r = tid >> 5;       // 0..7
    int kq = tid & 31;      // 4-elem chunk along k
    #pragma unroll
    for (int it = 0; it < 8; ++it){
      int rr = r + it * 8;
      int row = row0 + rr;
      float4 v = make_float4(0.f, 0.f, 0.f, 0.f);
      if (row < N){
        if (INBF){
          const uint* Au = (const uint*)Av;
          uint2 u = *(const uint2*)(Au + (size_t)row * 64 + kq * 2);
          float2 lo = bf2x2(u.x), hi = bf2x2(u.y);
          v = make_float4(lo.x, lo.y, hi.x, hi.y);
        } else {
          const float* Af = (const float*)Av;
          v = *(const float4*)(Af + (size_t)row * 128 + kq * 4);
        }
      }
      *(float4*)&Als[rr * 132 + kq * 4] = v;
    }
  }
  __syncthreads();
  int ct = tid & 15;
  int rt = tid >> 4;        // 0..15
  int c0 = ct * 4;
  float acc[4][8] = {};
  for (int k0 = 0; k0 < 128; k0 += 4){
    float a_[4][4];
    #pragma unroll
    for (int u = 0; u < 4; ++u){
      float4 av = *(const float4*)&Als[(rt * 4 + u) * 132 + k0];
      a_[u][0] = av.x; a_[u][1] = av.y; a_[u][2] = av.z; a_[u][3] = av.w;
    }
    #pragma unroll
    for (int kk = 0; kk < 4; ++kk){
      const float* Bk = B + (k0 + kk) * 128;
      float4 b0 = *(const float4*)(Bk + c0);
      float4 b1 = *(const float4*)(Bk + 64 + c0);
      float bb[8] = {b0.x, b0.y, b0.z, b0.w, b1.x, b1.y, b1.z, b1.w};
      #pragma unroll
      for (int u = 0; u < 4; ++u){
        float av = a_[u][kk];
        #pragma unroll
        for (int v = 0; v < 8; ++v) acc[u][v] += av * bb[v];
      }
    }
  }
  float bv[8];
  if (BIAS){
    float4 t0 = *(const float4*)(bias + c0);
    float4 t1 = *(const float4*)(bias + 64 + c0);
    bv[0] = t0.x; bv[1] = t0.y; bv[2] = t0.z; bv[3] = t0.w;
    bv[4] = t1.x; bv[5] = t1.y; bv[6] = t1.z; bv[7] = t1.w;
  } else {
    #pragma unroll
    for (int v = 0; v < 8; ++v) bv[v] = 0.f;
  }
  #pragma unroll
  for (int u = 0; u < 4; ++u){
    int row = row0 + rt * 4 + u;
    if (row < N){
      float o[8];
      #pragma unroll
      for (int v = 0; v < 8; ++v){
        float t = acc[u][v] + bv[v];
        if (RELU) t = fmaxf(t, 0.f);
        o[v] = t;
      }
      uint2 w0 = make_uint2(f2bf2(o[0], o[1]), f2bf2(o[2], o[3]));
      uint2 w1 = make_uint2(f2bf2(o[4], o[5]), f2bf2(o[6], o[7]));
      *(uint2*)(C16 + (size_t)row * 64 + ct * 2)      = w0;
      *(uint2*)(C16 + (size_t)row * 64 + 32 + ct * 2) = w1;
    }
  }
}

// ---------------- GAT layer (one wave per node, online softmax, bf16 gathers) ----------------
__global__ __launch_bounds__(256) void k_gat(float* __restrict__ H,
                      const uint* __restrict__ HWh, const uint* __restrict__ HAh,
                      const int* __restrict__ off, const int* __restrict__ srcs,
                      const float* __restrict__ GW, const float* __restrict__ GB){
  int n = blockIdx.x * 4 + (threadIdx.x >> 6);
  if (n >= NN) return;
  int lane = threadIdx.x & 63;
  float2 a = bf2x2(HAh[(size_t)n * 64 + lane]);
  int e0 = off[n], e1 = off[n + 1];
  int deg = e1 - e0;
  int myidx = (lane < deg) ? srcs[e0 + lane] : 0;
  float m = -INFINITY, den = 0.f, acc0 = 0.f, acc1 = 0.f;
  uint wu = 0;
  if (deg > 0){
    int s0 = __shfl(myidx, 0);
    wu = HWh[(size_t)s0 * 64 + lane];
  }
  for (int t = 0; t < deg; ++t){
    uint wnow = wu;
    if (t + 1 < deg){
      int s;
      if (t + 1 < 64) s = __shfl(myidx, t + 1);
      else s = srcs[e0 + t + 1];
      wu = HWh[(size_t)s * 64 + lane];
    }
    float2 w = bf2x2(wnow);
    float p = wsum(a.x * w.x + a.y * w.y);
    float mn = fmaxf(m, p);
    float cf = __expf(m - mn);   // exp(-inf)=0 on first edge
    float ex = __expf(p - mn);
    den  = den  * cf + ex;
    acc0 = acc0 * cf + ex * w.x;
    acc1 = acc1 * cf + ex * w.y;
    m = mn;
  }
  float inv = 1.f / (den + 1e-16f);
  float hp0 = fmaxf(acc0 * inv, 0.f), hp1 = fmaxf(acc1 * inv, 0.f);
  float2 x = *(const float2*)(H + (size_t)n * 128 + 2 * lane);
  float2 gx = *(const float2*)(GW + 2 * lane);
  float2 gh = *(const float2*)(GW + 128 + 2 * lane);
  float g = wsum(x.x * gx.x + x.y * gx.y + hp0 * gh.x + hp1 * gh.y) + GB[0];
  float z = 1.f / (1.f + __expf(-g));
  *(float2*)(H + (size_t)n * 128 + 2 * lane) =
      make_float2(z * x.x + (1.f - z) * hp0, z * x.y + (1.f - z) * hp1);
}

// ---------------- interaction layer ----------------
__global__ __launch_bounds__(256) void k_inter(float* __restrict__ H, const uint* __restrict__ Th,
                        const int* __restrict__ off, const int* __restrict__ srcs,
                        const float* __restrict__ GW, const float* __restrict__ GB){
  int n = blockIdx.x * 4 + (threadIdx.x >> 6);
  if (n >= NN) return;
  int lane = threadIdx.x & 63;
  int e0 = off[n], e1 = off[n + 1];
  int deg = e1 - e0;
  int myidx = (lane < deg) ? srcs[e0 + lane] : 0;
  float m0 = 0.f, m1 = 0.f;
  uint wu = 0;
  if (deg > 0){
    int s0 = __shfl(myidx, 0);
    wu = Th[(size_t)s0 * 64 + lane];
  }
  for (int t = 0; t < deg; ++t){
    uint wnow = wu;
    if (t + 1 < deg){
      int s;
      if (t + 1 < 64) s = __shfl(myidx, t + 1);
      else s = srcs[e0 + t + 1];
      wu = Th[(size_t)s * 64 + lane];
    }
    float2 w = bf2x2(wnow);
    m0 += w.x;
    m1 += w.y;
  }
  float2 x = *(const float2*)(H + (size_t)n * 128 + 2 * lane);
  float2 gx = *(const float2*)(GW + 2 * lane);
  float2 gh = *(const float2*)(GW + 128 + 2 * lane);
  float g = wsum(x.x * gx.x + x.y * gx.y + m0 * gh.x + m1 * gh.y) + GB[0];
  float z = 1.f / (1.f + __expf(-g));
  *(float2*)(H + (size_t)n * 128 + 2 * lane) =
      make_float2(z * x.x + (1.f - z) * m0, z * x.y + (1.f - z) * m1);
}

// ---------------- final inter-graph edges (2-deep pipelined) ----------------
__global__ __launch_bounds__(256) void k_edges(
    const int* __restrict__ EI,
    const float4* __restrict__ PRAD, const uint* __restrict__ MB,
    const uint* __restrict__ Pd, const uint* __restrict__ Qd,
    const uint* __restrict__ Pe, const uint* __restrict__ Qe,
    const float* __restrict__ w2d, const float* __restrict__ b2d,
    const float* __restrict__ w2e, const float* __restrict__ b2e,
    const float* __restrict__ hbc, const float* __restrict__ hpc,
    float* __restrict__ geng, float* __restrict__ outdv){
  __shared__ float eg[NG * 4];
  int tid = threadIdx.x;
  for (int i = tid; i < NG * 4; i += 256) eg[i] = 0.f;
  __syncthreads();
  int lane = tid & 63;
  int wid = blockIdx.x * 4 + (tid >> 6);
  int nw = gridDim.x * 4;
  float2 wd = *(const float2*)(w2d + 2 * lane);
  float2 we = *(const float2*)(w2e + 2 * lane);
  float bd = b2d[0], be = b2e[0];
  float minhb = -hbc[0] * hbc[0], minhp = -hpc[0] * hpc[0];

  int e = wid;
  int i0 = 0, j0 = 0, i1 = 0, j1 = 0;
  float4 pri0 = {}, prj0 = {};
  uint mbi0 = 0, mbj0 = 0;
  uint pd0 = 0, qd0 = 0, pe0 = 0, qe0 = 0;
  if (e < EIN){
    i0 = EI[e]; j0 = EI[EIN + e];
    pd0 = Pd[(size_t)i0 * 64 + lane]; qd0 = Qd[(size_t)j0 * 64 + lane];
    pe0 = Pe[(size_t)i0 * 64 + lane]; qe0 = Qe[(size_t)j0 * 64 + lane];
    pri0 = PRAD[i0]; prj0 = PRAD[j0]; mbi0 = MB[i0]; mbj0 = MB[j0];
  }
  if (e + nw < EIN){ i1 = EI[e + nw]; j1 = EI[EIN + e + nw]; }

  for (; e < EIN; e += nw){
    // prefetch: gathers for e+nw, indices for e+2*nw
    uint pd1 = 0, qd1 = 0, pe1 = 0, qe1 = 0;
    float4 pri1 = {}, prj1 = {};
    uint mbi1 = 0, mbj1 = 0;
    int i2 = 0, j2 = 0;
    if (e + nw < EIN){
      pd1 = Pd[(size_t)i1 * 64 + lane]; qd1 = Qd[(size_t)j1 * 64 + lane];
      pe1 = Pe[(size_t)i1 * 64 + lane]; qe1 = Qe[(size_t)j1 * 64 + lane];
      pri1 = PRAD[i1]; prj1 = PRAD[j1]; mbi1 = MB[i1]; mbj1 = MB[j1];
    }
    if (e + 2 * nw < EIN){ i2 = EI[e + 2 * nw]; j2 = EI[EIN + e + 2 * nw]; }

    // compute current edge
    float2 pdv = bf2x2(pd0), qdv = bf2x2(qd0), pev = bf2x2(pe0), qev = bf2x2(qe0);
    float hd0 = fmaxf(pdv.x + qdv.x, 0.f), hd1 = fmaxf(pdv.y + qdv.y, 0.f);
    float he0 = fmaxf(pev.x + qev.x, 0.f), he1 = fmaxf(pev.y + qev.y, 0.f);
    float sd = hd0 * wd.x + hd1 * wd.y;
    float se = he0 * we.x + he1 * we.y;
    #pragma unroll
    for (int o = 32; o; o >>= 1){
      sd += __shfl_xor(sd, o, 64);
      se += __shfl_xor(se, o, 64);
    }
    sd += bd; se += be;
    float dx = pri0.x - prj0.x, dy = pri0.y - prj0.y, dz = pri0.z - prj0.z;
    float D = sqrtf(dx * dx + dy * dy + dz * dz + 1e-10f);
    float rmask = (D >= 0.5f && D <= 5.0f) ? 1.f : 0.f;
    float dvdw = tanhf(sd) * DEV_VDW * rmask;
    float eps = (1.f / (1.f + __expf(-se))) * (EPS_HI_ - EPS_LO_) + EPS_LO_;
    if (lane == 0) outdv[e] = dvdw;
    float R = pri0.w + prj0.w + dvdw;
    float dr = fmaxf(D / R, 0.5f);
    float nn2 = (dr < 1.f) ? 10.f : 6.f;
    float tp = __expf(-nn2 * __logf(dr));
    float ev = eps * (tp * tp - 2.f * tp);
    float dmr = D - R;
    float f1 = fminf(fmaxf(dmr * (-1.f / 0.7f), 0.f), 1.f);
    float f3 = fminf(fmaxf(1.5f - dmr, 0.f), 1.f);
    bool metI = mbi0 & 1, metJ = mbj0 & 1;
    bool donI = mbi0 & 2, donJ = mbj0 & 2;
    bool accI = mbi0 & 4, accJ = mbj0 & 4;
    bool hyI  = mbi0 & 8, hyJ  = mbj0 & 8;
    bool nm = !(metI || metJ);
    float E0 = nm ? ev * rmask : 0.f;
    float E1 = (((donI && accJ) || (accI && donJ)) && nm) ? minhb * f1 * rmask : 0.f;
    float E2 = ((metI && accJ) || (accI && metJ)) ? minhb * f1 * rmask : 0.f;
    float E3 = (hyI && hyJ && nm) ? minhp * f3 * rmask : 0.f;
    if (lane == 0){
      int g = (int)(mbi0 >> 8) * 4;
      atomicAdd(&eg[g + 0], E0);
      atomicAdd(&eg[g + 1], E1);
      atomicAdd(&eg[g + 2], E2);
      atomicAdd(&eg[g + 3], E3);
    }
    // rotate pipeline
    i0 = i1; j0 = j1;
    pd0 = pd1; qd0 = qd1; pe0 = pe1; qe0 = qe1;
    pri0 = pri1; prj0 = prj1; mbi0 = mbi1; mbj0 = mbj1;
    i1 = i2; j1 = j2;
  }
  __syncthreads();
  for (int i2 = tid; i2 < NG * 4; i2 += 256) atomicAdd(&geng[i2], eg[i2]);
}

__global__ void k_final(const float* __restrict__ geng, const float* __restrict__ rotor,
                        const float* __restrict__ rc, float* __restrict__ out){
  int t = blockIdx.x * blockDim.x + threadIdx.x;
  if (t < NG * 4){
    int g = t >> 2;
    float pen = 1.f + rc[0] * rc[0] * rotor[g];
    out[t] = geng[t] / pen;
  }
}

extern "C" void kernel_launch(void* const* d_in, const int* in_sizes, int n_in,
                              void* d_out, int out_size, void* d_ws, size_t ws_size,
                              hipStream_t stream){
  (void)in_sizes; (void)n_in; (void)out_size; (void)ws_size;
  const float* X    = (const float*)d_in[0];
  const float* POS  = (const float*)d_in[1];
  const float* RAD  = (const float*)d_in[2];
  const float* ROT  = (const float*)d_in[3];
  const int* EIa    = (const int*)d_in[4];
  const int* EIc    = (const int*)d_in[5];
  const int* EIi    = (const int*)d_in[6];
  const int* BATCH  = (const int*)d_in[7];
  const int* Mmet = (const int*)d_in[8];
  const int* Mdon = (const int*)d_in[9];
  const int* Macc = (const int*)d_in[10];
  const int* Mhyd = (const int*)d_in[11];
  const float* embW  = (const float*)d_in[12];
  const float* gatW  = (const float*)d_in[13];
  const float* gatWb = (const float*)d_in[14];
  const float* gatA  = (const float*)d_in[15];
  const float* gatGw = (const float*)d_in[16];
  const float* gatGb = (const float*)d_in[17];
  const float* intW  = (const float*)d_in[18];
  const float* intWb = (const float*)d_in[19];
  const float* intGw = (const float*)d_in[20];
  const float* intGb = (const float*)d_in[21];
  const float* ew1 = (const float*)d_in[22];
  const float* eb1 = (const float*)d_in[23];
  const float* ew2 = (const float*)d_in[24];
  const float* eb2 = (const float*)d_in[25];
  const float* dw1 = (const float*)d_in[26];
  const float* db1 = (const float*)d_in[27];
  const float* dw2 = (const float*)d_in[28];
  const float* db2 = (const float*)d_in[29];
  const float* hbc = (const float*)d_in[30];
  const float* hpc = (const float*)d_in[31];
  const float* rcc = (const float*)d_in[32];
  float* out = (float*)d_out;

  char* w = (char*)d_ws;
  float* H   = (float*)w; w += (size_t)NN * 128 * 4;   // 25.6 MB
  uint* BAh  = (uint*)w;  w += (size_t)NN * 64 * 4;    // 12.8 MB (bf16 rows)
  uint* BBh  = (uint*)w;  w += (size_t)NN * 64 * 4;    // 12.8 MB
  uint* Peh  = (uint*)w;  w += (size_t)NN * 64 * 4;    // 12.8 MB
  uint* Qeh  = (uint*)w;  w += (size_t)NN * 64 * 4;    // 12.8 MB
  float4* PRAD = (float4*)w; w += (size_t)NN * 16;     // 0.8 MB
  uint* MB   = (uint*)w;  w += (size_t)NN * 4;         // 0.2 MB
  float* GENG = (float*)w; w += 512 * 4;
  int* cntA = (int*)w; w += (size_t)NN * 4;
  int* offA = (int*)w; w += (size_t)(NN + 1) * 4;
  int* curA = (int*)w; w += (size_t)NN * 4;
  int* srcA = (int*)w; w += (size_t)EA * 4;
  int* cntC = (int*)w; w += (size_t)NN * 4;
  int* offC = (int*)w; w += (size_t)(NN + 1) * 4;
  int* curC = (int*)w; w += (size_t)NN * 4;
  int* srcC = (int*)w; w += (size_t)EC * 4;
  uint* Th  = BAh;   // aliases: phases are sequential
  uint* Pdh = BAh;
  uint* Qdh = BBh;

  hipMemsetAsync(cntA, 0, (size_t)NN * 4, stream);
  hipMemsetAsync(cntC, 0, (size_t)NN * 4, stream);
  hipMemsetAsync(GENG, 0, 512 * 4, stream);

  k_count<<<1024, 256, 0, stream>>>(EIa + EA, EA, cntA);
  k_scan<<<1, 1024, 0, stream>>>(cntA, NN, offA, curA);
  k_place<<<1024, 256, 0, stream>>>(EIa, EIa + EA, EA, curA, srcA);
  k_count<<<1024, 256, 0, stream>>>(EIc + EC, EC, cntC);
  k_scan<<<1, 1024, 0, stream>>>(cntC, NN, offC, curC);
  k_place<<<1024, 256, 0, stream>>>(EIc, EIc + EC, EC, curC, srcC);

  k_nodeinfo<<<(NN + 255) / 256, 256, 0, stream>>>(POS, RAD, Mmet, Mdon, Macc, Mhyd, BATCH, PRAD, MB);
  k_embed<<<2048, 128, 0, stream>>>(X, embW, H);

  int gemmGrid = (NN + 63) / 64;
  for (int l = 0; l < 3; ++l){
    k_gemm<true,  false, false><<<gemmGrid, 256, 0, stream>>>(H,   gatW + l * 16384, gatWb + l * 128, BAh, NN);
    k_gemm<false, false, true ><<<gemmGrid, 256, 0, stream>>>(BAh, gatA + l * 16384, nullptr,         BBh, NN);
    k_gat<<<(NN + 3) / 4, 256, 0, stream>>>(H, BAh, BBh, offA, srcA, gatGw + l * 256, gatGb + l);
  }
  for (int l = 0; l < 3; ++l){
    k_gemm<true, true, false><<<gemmGrid, 256, 0, stream>>>(H, intW + l * 16384, intWb + l * 128, Th, NN);
    k_inter<<<(NN + 3) / 4, 256, 0, stream>>>(H, Th, offC, srcC, intGw + l * 256, intGb + l);
  }
  k_gemm<true,  false, false><<<gemmGrid, 256, 0, stream>>>(H, dw1,         db1,     Pdh, NN);
  k_gemm<false, false, false><<<gemmGrid, 256, 0, stream>>>(H, dw1 + 16384, nullptr, Qdh, NN);
  k_gemm<true,  false, false><<<gemmGrid, 256, 0, stream>>>(H, ew1,         eb1,     Peh, NN);
  k_gemm<false, false, false><<<gemmGrid, 256, 0, stream>>>(H, ew1 + 16384, nullptr, Qeh, NN);

  k_edges<<<1024, 256, 0, stream>>>(EIi, PRAD, MB, Pdh, Qdh, Peh, Qeh,
                                    dw2, db2, ew2, eb2, hbc, hpc,
                                    GENG, out + 512);
  k_final<<<2, 256, 0, stream>>>(GENG, ROT, rcc, out);
}

// Round 4
// 1102.427 us; speedup vs baseline: 1.4540x; 1.2333x over previous
//
#include <hip/hip_runtime.h>
#include <math.h>

#define NN 50000
#define EA 800000
#define EC 400000
#define EIN 600000
#define NG 128
#define FIN 54

#define DEV_VDW 0.2f
#define EPS_LO_ 0.0178f
#define EPS_HI_ 0.2f

typedef unsigned int uint;
typedef unsigned short ushort;

__device__ __forceinline__ float wsum(float v){
  #pragma unroll
  for (int o = 32; o; o >>= 1) v += __shfl_xor(v, o, 64);
  return v;
}

__device__ __forceinline__ ushort f2bf(float f){
  uint x = __float_as_uint(f);
  uint r = x + 0x7fffu + ((x >> 16) & 1u);
  return (ushort)(r >> 16);
}
__device__ __forceinline__ uint f2bf2(float a, float b){
  return (uint)f2bf(a) | ((uint)f2bf(b) << 16);
}
__device__ __forceinline__ float2 bf2x2(uint u){
  return make_float2(__uint_as_float(u << 16), __uint_as_float(u & 0xffff0000u));
}
__device__ __forceinline__ void decode8(uint4 u, float* f){
  f[0] = __uint_as_float(u.x << 16); f[1] = __uint_as_float(u.x & 0xffff0000u);
  f[2] = __uint_as_float(u.y << 16); f[3] = __uint_as_float(u.y & 0xffff0000u);
  f[4] = __uint_as_float(u.z << 16); f[5] = __uint_as_float(u.z & 0xffff0000u);
  f[6] = __uint_as_float(u.w << 16); f[7] = __uint_as_float(u.w & 0xffff0000u);
}

// ---------------- CSR build ----------------
__global__ void k_count(const int* __restrict__ dst, int E, int* __restrict__ cnt){
  int i = blockIdx.x * blockDim.x + threadIdx.x;
  int stride = gridDim.x * blockDim.x;
  for (; i < E; i += stride) atomicAdd(&cnt[dst[i]], 1);
}

__global__ void k_scan(const int* __restrict__ cnt, int n, int* __restrict__ off, int* __restrict__ cur){
  __shared__ int wsums[16];
  __shared__ int run_s;
  int tid = threadIdx.x;            // 1024
  int lane = tid & 63, w = tid >> 6;
  if (tid == 0) run_s = 0;
  __syncthreads();
  for (int base = 0; base < n; base += 1024){
    int run = run_s;
    int i = base + tid;
    int v = (i < n) ? cnt[i] : 0;
    int s = v;
    #pragma unroll
    for (int o = 1; o < 64; o <<= 1){ int t = __shfl_up(s, o, 64); if (lane >= o) s += t; }
    if (lane == 63) wsums[w] = s;
    __syncthreads();
    if (w == 0 && lane < 16){
      int t = wsums[lane];
      #pragma unroll
      for (int o = 1; o < 16; o <<= 1){ int u = __shfl_up(t, o, 64); if (lane >= o) t += u; }
      wsums[lane] = t;
    }
    __syncthreads();
    int woff = (w == 0) ? 0 : wsums[w - 1];
    int excl = run + woff + (s - v);
    if (i < n){ off[i] = excl; cur[i] = excl; }
    int tot = wsums[15];
    __syncthreads();
    if (tid == 0) run_s = run + tot;
    __syncthreads();
  }
  if (threadIdx.x == 0) off[n] = run_s;
}

__global__ void k_place(const int* __restrict__ src, const int* __restrict__ dst, int E,
                        int* __restrict__ cur, int* __restrict__ out_src){
  int i = blockIdx.x * blockDim.x + threadIdx.x;
  int stride = gridDim.x * blockDim.x;
  for (; i < E; i += stride){
    int d = dst[i];
    int slot = atomicAdd(&cur[d], 1);
    out_src[slot] = src[i];
  }
}

// ---------------- node static info ----------------
__global__ void k_nodeinfo(const float* __restrict__ POS, const float* __restrict__ RAD,
                           const int* __restrict__ Mmet, const int* __restrict__ Mdon,
                           const int* __restrict__ Macc, const int* __restrict__ Mhyd,
                           const int* __restrict__ BATCH,
                           float4* __restrict__ PRAD, uint* __restrict__ MB){
  int n = blockIdx.x * 256 + threadIdx.x;
  if (n < NN){
    PRAD[n] = make_float4(POS[3*n], POS[3*n+1], POS[3*n+2], RAD[n]);
    uint m = (Mmet[n] ? 1u : 0u) | (Mdon[n] ? 2u : 0u) | (Macc[n] ? 4u : 0u) |
             (Mhyd[n] ? 8u : 0u) | ((uint)BATCH[n] << 8);
    MB[n] = m;
  }
}

// ---------------- embed: H = X[NN,54] @ W[54,128] ----------------
__global__ void k_embed(const float* __restrict__ X, const float* __restrict__ W, float* __restrict__ H){
  __shared__ float Wls[FIN * 128];
  int tid = threadIdx.x; // 128
  for (int i = tid; i < FIN * 128; i += 128) Wls[i] = W[i];
  __syncthreads();
  for (int row = blockIdx.x; row < NN; row += gridDim.x){
    const float* xr = X + row * FIN;
    float acc = 0.f;
    #pragma unroll
    for (int k = 0; k < FIN; ++k) acc += xr[k] * Wls[k * 128 + tid];
    H[(size_t)row * 128 + tid] = acc;
  }
}

// ---------------- GEMM: C16[N,128](bf16) = act(A[N,128] @ B[128,128] + bias) ----------------
template<bool BIAS, bool RELU, bool INBF>
__global__ __launch_bounds__(256) void k_gemm(const void* __restrict__ Av, const float* __restrict__ B,
                                              const float* __restrict__ bias, uint* __restrict__ C16, int N){
  __shared__ float Als[64 * 132];
  int tid = threadIdx.x;
  int row0 = blockIdx.x * 64;
  {
    int r = tid >> 5;       // 0..7
    int kq = tid & 31;      // 4-elem chunk along k
    #pragma unroll
    for (int it = 0; it < 8; ++it){
      int rr = r + it * 8;
      int row = row0 + rr;
      float4 v = make_float4(0.f, 0.f, 0.f, 0.f);
      if (row < N){
        if (INBF){
          const uint* Au = (const uint*)Av;
          uint2 u = *(const uint2*)(Au + (size_t)row * 64 + kq * 2);
          float2 lo = bf2x2(u.x), hi = bf2x2(u.y);
          v = make_float4(lo.x, lo.y, hi.x, hi.y);
        } else {
          const float* Af = (const float*)Av;
          v = *(const float4*)(Af + (size_t)row * 128 + kq * 4);
        }
      }
      *(float4*)&Als[rr * 132 + kq * 4] = v;
    }
  }
  __syncthreads();
  int ct = tid & 15;
  int rt = tid >> 4;        // 0..15
  int c0 = ct * 4;
  float acc[4][8] = {};
  for (int k0 = 0; k0 < 128; k0 += 4){
    float a_[4][4];
    #pragma unroll
    for (int u = 0; u < 4; ++u){
      float4 av = *(const float4*)&Als[(rt * 4 + u) * 132 + k0];
      a_[u][0] = av.x; a_[u][1] = av.y; a_[u][2] = av.z; a_[u][3] = av.w;
    }
    #pragma unroll
    for (int kk = 0; kk < 4; ++kk){
      const float* Bk = B + (k0 + kk) * 128;
      float4 b0 = *(const float4*)(Bk + c0);
      float4 b1 = *(const float4*)(Bk + 64 + c0);
      float bb[8] = {b0.x, b0.y, b0.z, b0.w, b1.x, b1.y, b1.z, b1.w};
      #pragma unroll
      for (int u = 0; u < 4; ++u){
        float av = a_[u][kk];
        #pragma unroll
        for (int v = 0; v < 8; ++v) acc[u][v] += av * bb[v];
      }
    }
  }
  float bv[8];
  if (BIAS){
    float4 t0 = *(const float4*)(bias + c0);
    float4 t1 = *(const float4*)(bias + 64 + c0);
    bv[0] = t0.x; bv[1] = t0.y; bv[2] = t0.z; bv[3] = t0.w;
    bv[4] = t1.x; bv[5] = t1.y; bv[6] = t1.z; bv[7] = t1.w;
  } else {
    #pragma unroll
    for (int v = 0; v < 8; ++v) bv[v] = 0.f;
  }
  #pragma unroll
  for (int u = 0; u < 4; ++u){
    int row = row0 + rt * 4 + u;
    if (row < N){
      float o[8];
      #pragma unroll
      for (int v = 0; v < 8; ++v){
        float t = acc[u][v] + bv[v];
        if (RELU) t = fmaxf(t, 0.f);
        o[v] = t;
      }
      uint2 w0 = make_uint2(f2bf2(o[0], o[1]), f2bf2(o[2], o[3]));
      uint2 w1 = make_uint2(f2bf2(o[4], o[5]), f2bf2(o[6], o[7]));
      *(uint2*)(C16 + (size_t)row * 64 + ct * 2)      = w0;
      *(uint2*)(C16 + (size_t)row * 64 + 32 + ct * 2) = w1;
    }
  }
}

// ---------------- GAT layer: 16 lanes per node, 4 nodes per wave ----------------
__global__ __launch_bounds__(256) void k_gat(float* __restrict__ H,
                      const uint* __restrict__ HWh, const uint* __restrict__ HAh,
                      const int* __restrict__ off, const int* __restrict__ srcs,
                      const float* __restrict__ GW, const float* __restrict__ GB){
  int tid = threadIdx.x;
  int sub = tid & 15;
  int n = blockIdx.x * 16 + (tid >> 4);
  if (n >= NN) return;
  uint4 au = *(const uint4*)(HAh + (size_t)n * 64 + sub * 4);
  float a[8]; decode8(au, a);
  int e0 = off[n], deg = off[n + 1] - e0;
  float m = -INFINITY, den = 0.f;
  float acc[8] = {};
  uint4 wu = {};
  if (deg > 0){
    int s = srcs[e0];
    wu = *(const uint4*)(HWh + (size_t)s * 64 + sub * 4);
  }
  for (int t = 0; t < deg; ++t){
    uint4 wnow = wu;
    if (t + 1 < deg){
      int s2 = srcs[e0 + t + 1];
      wu = *(const uint4*)(HWh + (size_t)s2 * 64 + sub * 4);
    }
    float w[8]; decode8(wnow, w);
    float p = a[0]*w[0] + a[1]*w[1] + a[2]*w[2] + a[3]*w[3]
            + a[4]*w[4] + a[5]*w[5] + a[6]*w[6] + a[7]*w[7];
    #pragma unroll
    for (int o = 8; o; o >>= 1) p += __shfl_xor(p, o, 64);
    float mn = fmaxf(m, p);
    float cf = __expf(m - mn);   // exp(-inf)=0 on first edge
    float ex = __expf(p - mn);
    den = den * cf + ex;
    #pragma unroll
    for (int q = 0; q < 8; ++q) acc[q] = acc[q] * cf + ex * w[q];
    m = mn;
  }
  float inv = 1.f / (den + 1e-16f);
  float hp[8];
  #pragma unroll
  for (int q = 0; q < 8; ++q) hp[q] = fmaxf(acc[q] * inv, 0.f);
  float x[8];
  *(float4*)&x[0] = *(const float4*)(H + (size_t)n * 128 + sub * 8);
  *(float4*)&x[4] = *(const float4*)(H + (size_t)n * 128 + sub * 8 + 4);
  float gx[8], gh[8];
  *(float4*)&gx[0] = *(const float4*)(GW + sub * 8);
  *(float4*)&gx[4] = *(const float4*)(GW + sub * 8 + 4);
  *(float4*)&gh[0] = *(const float4*)(GW + 128 + sub * 8);
  *(float4*)&gh[4] = *(const float4*)(GW + 128 + sub * 8 + 4);
  float g = 0.f;
  #pragma unroll
  for (int q = 0; q < 8; ++q) g += x[q] * gx[q] + hp[q] * gh[q];
  #pragma unroll
  for (int o = 8; o; o >>= 1) g += __shfl_xor(g, o, 64);
  g += GB[0];
  float z = 1.f / (1.f + __expf(-g));
  #pragma unroll
  for (int q = 0; q < 8; ++q) x[q] = z * x[q] + (1.f - z) * hp[q];
  *(float4*)(H + (size_t)n * 128 + sub * 8)     = *(float4*)&x[0];
  *(float4*)(H + (size_t)n * 128 + sub * 8 + 4) = *(float4*)&x[4];
}

// ---------------- interaction layer: 16 lanes per node ----------------
__global__ __launch_bounds__(256) void k_inter(float* __restrict__ H, const uint* __restrict__ Th,
                        const int* __restrict__ off, const int* __restrict__ srcs,
                        const float* __restrict__ GW, const float* __restrict__ GB){
  int tid = threadIdx.x;
  int sub = tid & 15;
  int n = blockIdx.x * 16 + (tid >> 4);
  if (n >= NN) return;
  int e0 = off[n], deg = off[n + 1] - e0;
  float acc[8] = {};
  uint4 wu = {};
  if (deg > 0){
    int s = srcs[e0];
    wu = *(const uint4*)(Th + (size_t)s * 64 + sub * 4);
  }
  for (int t = 0; t < deg; ++t){
    uint4 wnow = wu;
    if (t + 1 < deg){
      int s2 = srcs[e0 + t + 1];
      wu = *(const uint4*)(Th + (size_t)s2 * 64 + sub * 4);
    }
    float w[8]; decode8(wnow, w);
    #pragma unroll
    for (int q = 0; q < 8; ++q) acc[q] += w[q];
  }
  float x[8];
  *(float4*)&x[0] = *(const float4*)(H + (size_t)n * 128 + sub * 8);
  *(float4*)&x[4] = *(const float4*)(H + (size_t)n * 128 + sub * 8 + 4);
  float gx[8], gh[8];
  *(float4*)&gx[0] = *(const float4*)(GW + sub * 8);
  *(float4*)&gx[4] = *(const float4*)(GW + sub * 8 + 4);
  *(float4*)&gh[0] = *(const float4*)(GW + 128 + sub * 8);
  *(float4*)&gh[4] = *(const float4*)(GW + 128 + sub * 8 + 4);
  float g = 0.f;
  #pragma unroll
  for (int q = 0; q < 8; ++q) g += x[q] * gx[q] + acc[q] * gh[q];
  #pragma unroll
  for (int o = 8; o; o >>= 1) g += __shfl_xor(g, o, 64);
  g += GB[0];
  float z = 1.f / (1.f + __expf(-g));
  #pragma unroll
  for (int q = 0; q < 8; ++q) x[q] = z * x[q] + (1.f - z) * acc[q];
  *(float4*)(H + (size_t)n * 128 + sub * 8)     = *(float4*)&x[0];
  *(float4*)(H + (size_t)n * 128 + sub * 8 + 4) = *(float4*)&x[4];
}

// ---------------- final inter-graph edges: 16 lanes per edge, 1-deep pipeline ----------------
__global__ __launch_bounds__(256) void k_edges(
    const int* __restrict__ EI,
    const float4* __restrict__ PRAD, const uint* __restrict__ MB,
    const uint* __restrict__ Pd, const uint* __restrict__ Qd,
    const uint* __restrict__ Pe, const uint* __restrict__ Qe,
    const float* __restrict__ w2d, const float* __restrict__ b2d,
    const float* __restrict__ w2e, const float* __restrict__ b2e,
    const float* __restrict__ hbc, const float* __restrict__ hpc,
    float* __restrict__ geng, float* __restrict__ outdv){
  __shared__ float eg[NG * 4];
  int tid = threadIdx.x;
  for (int i = tid; i < NG * 4; i += 256) eg[i] = 0.f;
  __syncthreads();
  int sub = tid & 15;
  int gid = blockIdx.x * 16 + (tid >> 4);
  int ngrp = gridDim.x * 16;
  float wdv[8], wev[8];
  *(float4*)&wdv[0] = *(const float4*)(w2d + sub * 8);
  *(float4*)&wdv[4] = *(const float4*)(w2d + sub * 8 + 4);
  *(float4*)&wev[0] = *(const float4*)(w2e + sub * 8);
  *(float4*)&wev[4] = *(const float4*)(w2e + sub * 8 + 4);
  float bd = b2d[0], be = b2e[0];
  float minhb = -hbc[0] * hbc[0], minhp = -hpc[0] * hpc[0];

  int e = gid;
  uint4 pd0 = {}, qd0 = {}, pe0 = {}, qe0 = {};
  float4 pri0 = {}, prj0 = {};
  uint mbi0 = 0, mbj0 = 0;
  int i1 = 0, j1 = 0;
  if (e < EIN){
    int i0 = EI[e], j0 = EI[EIN + e];
    pd0 = *(const uint4*)(Pd + (size_t)i0 * 64 + sub * 4);
    qd0 = *(const uint4*)(Qd + (size_t)j0 * 64 + sub * 4);
    pe0 = *(const uint4*)(Pe + (size_t)i0 * 64 + sub * 4);
    qe0 = *(const uint4*)(Qe + (size_t)j0 * 64 + sub * 4);
    pri0 = PRAD[i0]; prj0 = PRAD[j0]; mbi0 = MB[i0]; mbj0 = MB[j0];
  }
  if (e + ngrp < EIN){ i1 = EI[e + ngrp]; j1 = EI[EIN + e + ngrp]; }

  for (; e < EIN; e += ngrp){
    uint4 pd1 = {}, qd1 = {}, pe1 = {}, qe1 = {};
    float4 pri1 = {}, prj1 = {};
    uint mbi1 = 0, mbj1 = 0;
    int i2 = 0, j2 = 0;
    if (e + ngrp < EIN){
      pd1 = *(const uint4*)(Pd + (size_t)i1 * 64 + sub * 4);
      qd1 = *(const uint4*)(Qd + (size_t)j1 * 64 + sub * 4);
      pe1 = *(const uint4*)(Pe + (size_t)i1 * 64 + sub * 4);
      qe1 = *(const uint4*)(Qe + (size_t)j1 * 64 + sub * 4);
      pri1 = PRAD[i1]; prj1 = PRAD[j1]; mbi1 = MB[i1]; mbj1 = MB[j1];
    }
    if (e + 2 * ngrp < EIN){ i2 = EI[e + 2 * ngrp]; j2 = EI[EIN + e + 2 * ngrp]; }

    float pdf[8], qdf[8], pef[8], qef[8];
    decode8(pd0, pdf); decode8(qd0, qdf); decode8(pe0, pef); decode8(qe0, qef);
    float sd = 0.f, se = 0.f;
    #pragma unroll
    for (int q = 0; q < 8; ++q){
      sd += fmaxf(pdf[q] + qdf[q], 0.f) * wdv[q];
      se += fmaxf(pef[q] + qef[q], 0.f) * wev[q];
    }
    #pragma unroll
    for (int o = 8; o; o >>= 1){
      sd += __shfl_xor(sd, o, 64);
      se += __shfl_xor(se, o, 64);
    }
    sd += bd; se += be;
    float dx = pri0.x - prj0.x, dy = pri0.y - prj0.y, dz = pri0.z - prj0.z;
    float D = sqrtf(dx * dx + dy * dy + dz * dz + 1e-10f);
    float rmask = (D >= 0.5f && D <= 5.0f) ? 1.f : 0.f;
    float dvdw = tanhf(sd) * DEV_VDW * rmask;
    float eps = (1.f / (1.f + __expf(-se))) * (EPS_HI_ - EPS_LO_) + EPS_LO_;
    float R = pri0.w + prj0.w + dvdw;
    float dr = fmaxf(D / R, 0.5f);
    float nn2 = (dr < 1.f) ? 10.f : 6.f;
    float tp = __expf(-nn2 * __logf(dr));
    float ev = eps * (tp * tp - 2.f * tp);
    float dmr = D - R;
    float f1 = fminf(fmaxf(dmr * (-1.f / 0.7f), 0.f), 1.f);
    float f3 = fminf(fmaxf(1.5f - dmr, 0.f), 1.f);
    bool metI = mbi0 & 1, metJ = mbj0 & 1;
    bool donI = mbi0 & 2, donJ = mbj0 & 2;
    bool accI = mbi0 & 4, accJ = mbj0 & 4;
    bool hyI  = mbi0 & 8, hyJ  = mbj0 & 8;
    bool nm = !(metI || metJ);
    float E0 = nm ? ev * rmask : 0.f;
    float E1 = (((donI && accJ) || (accI && donJ)) && nm) ? minhb * f1 * rmask : 0.f;
    float E2 = ((metI && accJ) || (accI && metJ)) ? minhb * f1 * rmask : 0.f;
    float E3 = (hyI && hyJ && nm) ? minhp * f3 * rmask : 0.f;
    if (sub == 0){
      outdv[e] = dvdw;
      int g = (int)(mbi0 >> 8) * 4;
      atomicAdd(&eg[g + 0], E0);
      atomicAdd(&eg[g + 1], E1);
      atomicAdd(&eg[g + 2], E2);
      atomicAdd(&eg[g + 3], E3);
    }
    pd0 = pd1; qd0 = qd1; pe0 = pe1; qe0 = qe1;
    pri0 = pri1; prj0 = prj1; mbi0 = mbi1; mbj0 = mbj1;
    i1 = i2; j1 = j2;
  }
  __syncthreads();
  for (int i2 = tid; i2 < NG * 4; i2 += 256) atomicAdd(&geng[i2], eg[i2]);
}

__global__ void k_final(const float* __restrict__ geng, const float* __restrict__ rotor,
                        const float* __restrict__ rc, float* __restrict__ out){
  int t = blockIdx.x * blockDim.x + threadIdx.x;
  if (t < NG * 4){
    int g = t >> 2;
    float pen = 1.f + rc[0] * rc[0] * rotor[g];
    out[t] = geng[t] / pen;
  }
}

extern "C" void kernel_launch(void* const* d_in, const int* in_sizes, int n_in,
                              void* d_out, int out_size, void* d_ws, size_t ws_size,
                              hipStream_t stream){
  (void)in_sizes; (void)n_in; (void)out_size; (void)ws_size;
  const float* X    = (const float*)d_in[0];
  const float* POS  = (const float*)d_in[1];
  const float* RAD  = (const float*)d_in[2];
  const float* ROT  = (const float*)d_in[3];
  const int* EIa    = (const int*)d_in[4];
  const int* EIc    = (const int*)d_in[5];
  const int* EIi    = (const int*)d_in[6];
  const int* BATCH  = (const int*)d_in[7];
  const int* Mmet = (const int*)d_in[8];
  const int* Mdon = (const int*)d_in[9];
  const int* Macc = (const int*)d_in[10];
  const int* Mhyd = (const int*)d_in[11];
  const float* embW  = (const float*)d_in[12];
  const float* gatW  = (const float*)d_in[13];
  const float* gatWb = (const float*)d_in[14];
  const float* gatA  = (const float*)d_in[15];
  const float* gatGw = (const float*)d_in[16];
  const float* gatGb = (const float*)d_in[17];
  const float* intW  = (const float*)d_in[18];
  const float* intWb = (const float*)d_in[19];
  const float* intGw = (const float*)d_in[20];
  const float* intGb = (const float*)d_in[21];
  const float* ew1 = (const float*)d_in[22];
  const float* eb1 = (const float*)d_in[23];
  const float* ew2 = (const float*)d_in[24];
  const float* eb2 = (const float*)d_in[25];
  const float* dw1 = (const float*)d_in[26];
  const float* db1 = (const float*)d_in[27];
  const float* dw2 = (const float*)d_in[28];
  const float* db2 = (const float*)d_in[29];
  const float* hbc = (const float*)d_in[30];
  const float* hpc = (const float*)d_in[31];
  const float* rcc = (const float*)d_in[32];
  float* out = (float*)d_out;

  char* w = (char*)d_ws;
  float* H   = (float*)w; w += (size_t)NN * 128 * 4;   // 25.6 MB
  uint* BAh  = (uint*)w;  w += (size_t)NN * 64 * 4;    // 12.8 MB (bf16 rows)
  uint* BBh  = (uint*)w;  w += (size_t)NN * 64 * 4;    // 12.8 MB
  uint* Peh  = (uint*)w;  w += (size_t)NN * 64 * 4;    // 12.8 MB
  uint* Qeh  = (uint*)w;  w += (size_t)NN * 64 * 4;    // 12.8 MB
  float4* PRAD = (float4*)w; w += (size_t)NN * 16;     // 0.8 MB
  uint* MB   = (uint*)w;  w += (size_t)NN * 4;         // 0.2 MB
  float* GENG = (float*)w; w += 512 * 4;
  int* cntA = (int*)w; w += (size_t)NN * 4;
  int* offA = (int*)w; w += (size_t)(NN + 1) * 4;
  int* curA = (int*)w; w += (size_t)NN * 4;
  int* srcA = (int*)w; w += (size_t)EA * 4;
  int* cntC = (int*)w; w += (size_t)NN * 4;
  int* offC = (int*)w; w += (size_t)(NN + 1) * 4;
  int* curC = (int*)w; w += (size_t)NN * 4;
  int* srcC = (int*)w; w += (size_t)EC * 4;
  uint* Th  = BAh;   // aliases: phases are sequential
  uint* Pdh = BAh;
  uint* Qdh = BBh;

  hipMemsetAsync(cntA, 0, (size_t)NN * 4, stream);
  hipMemsetAsync(cntC, 0, (size_t)NN * 4, stream);
  hipMemsetAsync(GENG, 0, 512 * 4, stream);

  k_count<<<1024, 256, 0, stream>>>(EIa + EA, EA, cntA);
  k_scan<<<1, 1024, 0, stream>>>(cntA, NN, offA, curA);
  k_place<<<1024, 256, 0, stream>>>(EIa, EIa + EA, EA, curA, srcA);
  k_count<<<1024, 256, 0, stream>>>(EIc + EC, EC, cntC);
  k_scan<<<1, 1024, 0, stream>>>(cntC, NN, offC, curC);
  k_place<<<1024, 256, 0, stream>>>(EIc, EIc + EC, EC, curC, srcC);

  k_nodeinfo<<<(NN + 255) / 256, 256, 0, stream>>>(POS, RAD, Mmet, Mdon, Macc, Mhyd, BATCH, PRAD, MB);
  k_embed<<<2048, 128, 0, stream>>>(X, embW, H);

  int gemmGrid = (NN + 63) / 64;
  int nodeGrid = (NN + 15) / 16;
  for (int l = 0; l < 3; ++l){
    k_gemm<true,  false, false><<<gemmGrid, 256, 0, stream>>>(H,   gatW + l * 16384, gatWb + l * 128, BAh, NN);
    k_gemm<false, false, true ><<<gemmGrid, 256, 0, stream>>>(BAh, gatA + l * 16384, nullptr,         BBh, NN);
    k_gat<<<nodeGrid, 256, 0, stream>>>(H, BAh, BBh, offA, srcA, gatGw + l * 256, gatGb + l);
  }
  for (int l = 0; l < 3; ++l){
    k_gemm<true, true, false><<<gemmGrid, 256, 0, stream>>>(H, intW + l * 16384, intWb + l * 128, Th, NN);
    k_inter<<<nodeGrid, 256, 0, stream>>>(H, Th, offC, srcC, intGw + l * 256, intGb + l);
  }
  k_gemm<true,  false, false><<<gemmGrid, 256, 0, stream>>>(H, dw1,         db1,     Pdh, NN);
  k_gemm<false, false, false><<<gemmGrid, 256, 0, stream>>>(H, dw1 + 16384, nullptr, Qdh, NN);
  k_gemm<true,  false, false><<<gemmGrid, 256, 0, stream>>>(H, ew1,         eb1,     Peh, NN);
  k_gemm<false, false, false><<<gemmGrid, 256, 0, stream>>>(H, ew1 + 16384, nullptr, Qeh, NN);

  k_edges<<<1024, 256, 0, stream>>>(EIi, PRAD, MB, Pdh, Qdh, Peh, Qeh,
                                    dw2, db2, ew2, eb2, hbc, hpc,
                                    GENG, out + 512);
  k_final<<<2, 256, 0, stream>>>(GENG, ROT, rcc, out);
}

// Round 5
// 852.798 us; speedup vs baseline: 1.8796x; 1.2927x over previous
//
#include <hip/hip_runtime.h>
#include <math.h>

#define NN 50000
#define EA 800000
#define EC 400000
#define EIN 600000
#define NG 128
#define FIN 54

#define DEV_VDW 0.2f
#define EPS_LO_ 0.0178f
#define EPS_HI_ 0.2f

typedef unsigned int uint;
typedef unsigned short ushort;
typedef __attribute__((ext_vector_type(8))) short bf16x8;
typedef __attribute__((ext_vector_type(4))) float f32x4;

__device__ __forceinline__ ushort f2bf(float f){
  uint x = __float_as_uint(f);
  uint r = x + 0x7fffu + ((x >> 16) & 1u);
  return (ushort)(r >> 16);
}
__device__ __forceinline__ uint f2bf2(float a, float b){
  return (uint)f2bf(a) | ((uint)f2bf(b) << 16);
}
__device__ __forceinline__ float2 bf2x2(uint u){
  return make_float2(__uint_as_float(u << 16), __uint_as_float(u & 0xffff0000u));
}
__device__ __forceinline__ void decode8(uint4 u, float* f){
  f[0] = __uint_as_float(u.x << 16); f[1] = __uint_as_float(u.x & 0xffff0000u);
  f[2] = __uint_as_float(u.y << 16); f[3] = __uint_as_float(u.y & 0xffff0000u);
  f[4] = __uint_as_float(u.z << 16); f[5] = __uint_as_float(u.z & 0xffff0000u);
  f[6] = __uint_as_float(u.w << 16); f[7] = __uint_as_float(u.w & 0xffff0000u);
}

// ---------------- CSR build ----------------
__global__ void k_count(const int* __restrict__ dst, int E, int* __restrict__ cnt){
  int i = blockIdx.x * blockDim.x + threadIdx.x;
  int stride = gridDim.x * blockDim.x;
  for (; i < E; i += stride) atomicAdd(&cnt[dst[i]], 1);
}

__global__ void k_scan(const int* __restrict__ cnt, int n, int* __restrict__ off, int* __restrict__ cur){
  __shared__ int wsums[16];
  __shared__ int run_s;
  int tid = threadIdx.x;            // 1024
  int lane = tid & 63, w = tid >> 6;
  if (tid == 0) run_s = 0;
  __syncthreads();
  for (int base = 0; base < n; base += 1024){
    int run = run_s;
    int i = base + tid;
    int v = (i < n) ? cnt[i] : 0;
    int s = v;
    #pragma unroll
    for (int o = 1; o < 64; o <<= 1){ int t = __shfl_up(s, o, 64); if (lane >= o) s += t; }
    if (lane == 63) wsums[w] = s;
    __syncthreads();
    if (w == 0 && lane < 16){
      int t = wsums[lane];
      #pragma unroll
      for (int o = 1; o < 16; o <<= 1){ int u = __shfl_up(t, o, 64); if (lane >= o) t += u; }
      wsums[lane] = t;
    }
    __syncthreads();
    int woff = (w == 0) ? 0 : wsums[w - 1];
    int excl = run + woff + (s - v);
    if (i < n){ off[i] = excl; cur[i] = excl; }
    int tot = wsums[15];
    __syncthreads();
    if (tid == 0) run_s = run + tot;
    __syncthreads();
  }
  if (threadIdx.x == 0) off[n] = run_s;
}

__global__ void k_place(const int* __restrict__ src, const int* __restrict__ dst, int E,
                        int* __restrict__ cur, int* __restrict__ out_src){
  int i = blockIdx.x * blockDim.x + threadIdx.x;
  int stride = gridDim.x * blockDim.x;
  for (; i < E; i += stride){
    int d = dst[i];
    int slot = atomicAdd(&cur[d], 1);
    out_src[slot] = src[i];
  }
}

// ---------------- node static info ----------------
__global__ void k_nodeinfo(const float* __restrict__ POS, const float* __restrict__ RAD,
                           const int* __restrict__ Mmet, const int* __restrict__ Mdon,
                           const int* __restrict__ Macc, const int* __restrict__ Mhyd,
                           const int* __restrict__ BATCH,
                           float4* __restrict__ PRAD, uint* __restrict__ MB){
  int n = blockIdx.x * 256 + threadIdx.x;
  if (n < NN){
    PRAD[n] = make_float4(POS[3*n], POS[3*n+1], POS[3*n+2], RAD[n]);
    uint m = (Mmet[n] ? 1u : 0u) | (Mdon[n] ? 2u : 0u) | (Macc[n] ? 4u : 0u) |
             (Mhyd[n] ? 8u : 0u) | ((uint)BATCH[n] << 8);
    MB[n] = m;
  }
}

// ---------------- weight prep: 13 x [128][128] f32 -> Wt [n][k] bf16; + bias4/zeros ----------------
__global__ __launch_bounds__(256) void k_prepw(const float* __restrict__ gatW, const float* __restrict__ gatA,
                        const float* __restrict__ intW, const float* __restrict__ dw1,
                        const float* __restrict__ ew1, const float* __restrict__ db1,
                        const float* __restrict__ eb1,
                        uint* __restrict__ Wt, float* __restrict__ BIASB){
  __shared__ ushort L[128 * 130];
  int m = blockIdx.x;
  int tid = threadIdx.x;
  if (m == 13){
    if (tid < 512){
      int c = tid & 127, y = tid >> 7;
      float v = (y == 0) ? db1[c] : (y == 2) ? eb1[c] : 0.f;
      BIASB[tid] = v;
    }
    if (tid < 128) BIASB[512 + tid] = 0.f;   // zeros128
    return;
  }
  const float* src = (m < 3)  ? gatW + m * 16384 :
                     (m < 6)  ? gatA + (m - 3) * 16384 :
                     (m < 9)  ? intW + (m - 6) * 16384 :
                     (m < 11) ? dw1 + (m - 9) * 16384 :
                                ew1 + (m - 11) * 16384;
  for (int idx = tid; idx < 16384; idx += 256){
    int k = idx >> 7, n = idx & 127;
    L[k * 130 + n] = f2bf(src[idx]);
  }
  __syncthreads();
  int n = tid & 127, half = tid >> 7;
  uint* outp = Wt + (size_t)m * 8192 + n * 64 + half * 32;
  #pragma unroll
  for (int kk2 = 0; kk2 < 32; ++kk2){
    int k = half * 64 + 2 * kk2;
    uint u = (uint)L[k * 130 + n] | ((uint)L[(k + 1) * 130 + n] << 16);
    outp[kk2] = u;
  }
}

// ---------------- embed: H = X[NN,54] @ W[54,128]; writes f32 H + bf16 Hh ----------------
__global__ void k_embed(const float* __restrict__ X, const float* __restrict__ W,
                        float* __restrict__ H, uint* __restrict__ Hh){
  __shared__ float Wls[FIN * 128];
  int tid = threadIdx.x; // 128
  for (int i = tid; i < FIN * 128; i += 128) Wls[i] = W[i];
  __syncthreads();
  for (int row = blockIdx.x; row < NN; row += gridDim.x){
    const float* xr = X + row * FIN;
    float acc = 0.f;
    #pragma unroll
    for (int k = 0; k < FIN; ++k) acc += xr[k] * Wls[k * 128 + tid];
    H[(size_t)row * 128 + tid] = acc;
    ((ushort*)Hh)[(size_t)row * 128 + tid] = f2bf(acc);
  }
}

// ---------------- MFMA GEMM: C16[N,128](bf16) = act(Ah[N,128](bf16) @ B + bias) ----------------
// Bt is [n][k] bf16 (pre-transposed). blockIdx.y selects (Bt,bias,C) set for fused multi-GEMM.
template<bool RELU>
__global__ __launch_bounds__(256) void k_gemm_mfma(const uint* __restrict__ Ah,
        const uint* __restrict__ Bt0, const float* __restrict__ bias0,
        uint* __restrict__ C0, size_t strideC, int N){
  const uint* Bt = Bt0 + (size_t)blockIdx.y * 8192;
  const float* bias = bias0 + (size_t)blockIdx.y * 128;
  uint* Cout = C0 + (size_t)blockIdx.y * strideC;
  int tid = threadIdx.x;
  int lane = tid & 63;
  int wv = tid >> 6;                      // 0..3
  int row0 = blockIdx.x * 128 + wv * 32;
  int l15 = lane & 15, lg = lane >> 4;
  int ra0 = row0 + l15, ra1 = row0 + 16 + l15;
  const uint* pa0 = Ah + (size_t)(ra0 < N ? ra0 : 0) * 64 + lg * 4;
  const uint* pa1 = Ah + (size_t)(ra1 < N ? ra1 : 0) * 64 + lg * 4;
  const uint* pb  = Bt + (size_t)l15 * 64 + lg * 4;
  f32x4 acc[2][8] = {};
  #pragma unroll
  for (int c = 0; c < 4; ++c){
    bf16x8 a0 = *(const bf16x8*)(pa0 + c * 16);
    bf16x8 a1 = *(const bf16x8*)(pa1 + c * 16);
    #pragma unroll
    for (int ct = 0; ct < 8; ++ct){
      bf16x8 b = *(const bf16x8*)(pb + ct * 1024 + c * 16);
      acc[0][ct] = __builtin_amdgcn_mfma_f32_16x16x32_bf16(a0, b, acc[0][ct], 0, 0, 0);
      acc[1][ct] = __builtin_amdgcn_mfma_f32_16x16x32_bf16(a1, b, acc[1][ct], 0, 0, 0);
    }
  }
  #pragma unroll
  for (int ct = 0; ct < 8; ++ct){
    int col = ct * 16 + l15;
    float bv = bias[col];
    #pragma unroll
    for (int rt = 0; rt < 2; ++rt){
      int rbase = row0 + rt * 16 + lg * 4;
      f32x4 a4 = acc[rt][ct];
      #pragma unroll
      for (int r = 0; r < 4; ++r){
        int row = rbase + r;
        if (row < N){
          float t = a4[r] + bv;
          if (RELU) t = fmaxf(t, 0.f);
          ((ushort*)Cout)[(size_t)row * 128 + col] = f2bf(t);
        }
      }
    }
  }
}

// ---------------- GAT layer: 16 lanes per node, 4 nodes per wave ----------------
__global__ __launch_bounds__(256) void k_gat(float* __restrict__ H, uint* __restrict__ Hh,
                      const uint* __restrict__ HWh, const uint* __restrict__ HAh,
                      const int* __restrict__ off, const int* __restrict__ srcs,
                      const float* __restrict__ GW, const float* __restrict__ GB){
  int tid = threadIdx.x;
  int sub = tid & 15;
  int n = blockIdx.x * 16 + (tid >> 4);
  if (n >= NN) return;
  uint4 au = *(const uint4*)(HAh + (size_t)n * 64 + sub * 4);
  float a[8]; decode8(au, a);
  int e0 = off[n], deg = off[n + 1] - e0;
  float m = -INFINITY, den = 0.f;
  float acc[8] = {};
  uint4 wu = {};
  if (deg > 0){
    int s = srcs[e0];
    wu = *(const uint4*)(HWh + (size_t)s * 64 + sub * 4);
  }
  for (int t = 0; t < deg; ++t){
    uint4 wnow = wu;
    if (t + 1 < deg){
      int s2 = srcs[e0 + t + 1];
      wu = *(const uint4*)(HWh + (size_t)s2 * 64 + sub * 4);
    }
    float w[8]; decode8(wnow, w);
    float p = a[0]*w[0] + a[1]*w[1] + a[2]*w[2] + a[3]*w[3]
            + a[4]*w[4] + a[5]*w[5] + a[6]*w[6] + a[7]*w[7];
    #pragma unroll
    for (int o = 8; o; o >>= 1) p += __shfl_xor(p, o, 64);
    float mn = fmaxf(m, p);
    float cf = __expf(m - mn);   // exp(-inf)=0 on first edge
    float ex = __expf(p - mn);
    den = den * cf + ex;
    #pragma unroll
    for (int q = 0; q < 8; ++q) acc[q] = acc[q] * cf + ex * w[q];
    m = mn;
  }
  float inv = 1.f / (den + 1e-16f);
  float hp[8];
  #pragma unroll
  for (int q = 0; q < 8; ++q) hp[q] = fmaxf(acc[q] * inv, 0.f);
  float x[8];
  *(float4*)&x[0] = *(const float4*)(H + (size_t)n * 128 + sub * 8);
  *(float4*)&x[4] = *(const float4*)(H + (size_t)n * 128 + sub * 8 + 4);
  float gx[8], gh[8];
  *(float4*)&gx[0] = *(const float4*)(GW + sub * 8);
  *(float4*)&gx[4] = *(const float4*)(GW + sub * 8 + 4);
  *(float4*)&gh[0] = *(const float4*)(GW + 128 + sub * 8);
  *(float4*)&gh[4] = *(const float4*)(GW + 128 + sub * 8 + 4);
  float g = 0.f;
  #pragma unroll
  for (int q = 0; q < 8; ++q) g += x[q] * gx[q] + hp[q] * gh[q];
  #pragma unroll
  for (int o = 8; o; o >>= 1) g += __shfl_xor(g, o, 64);
  g += GB[0];
  float z = 1.f / (1.f + __expf(-g));
  #pragma unroll
  for (int q = 0; q < 8; ++q) x[q] = z * x[q] + (1.f - z) * hp[q];
  *(float4*)(H + (size_t)n * 128 + sub * 8)     = *(float4*)&x[0];
  *(float4*)(H + (size_t)n * 128 + sub * 8 + 4) = *(float4*)&x[4];
  uint4 hw;
  hw.x = f2bf2(x[0], x[1]); hw.y = f2bf2(x[2], x[3]);
  hw.z = f2bf2(x[4], x[5]); hw.w = f2bf2(x[6], x[7]);
  *(uint4*)(Hh + (size_t)n * 64 + sub * 4) = hw;
}

// ---------------- interaction layer: 16 lanes per node ----------------
__global__ __launch_bounds__(256) void k_inter(float* __restrict__ H, uint* __restrict__ Hh,
                        const uint* __restrict__ Th,
                        const int* __restrict__ off, const int* __restrict__ srcs,
                        const float* __restrict__ GW, const float* __restrict__ GB){
  int tid = threadIdx.x;
  int sub = tid & 15;
  int n = blockIdx.x * 16 + (tid >> 4);
  if (n >= NN) return;
  int e0 = off[n], deg = off[n + 1] - e0;
  float acc[8] = {};
  uint4 wu = {};
  if (deg > 0){
    int s = srcs[e0];
    wu = *(const uint4*)(Th + (size_t)s * 64 + sub * 4);
  }
  for (int t = 0; t < deg; ++t){
    uint4 wnow = wu;
    if (t + 1 < deg){
      int s2 = srcs[e0 + t + 1];
      wu = *(const uint4*)(Th + (size_t)s2 * 64 + sub * 4);
    }
    float w[8]; decode8(wnow, w);
    #pragma unroll
    for (int q = 0; q < 8; ++q) acc[q] += w[q];
  }
  float x[8];
  *(float4*)&x[0] = *(const float4*)(H + (size_t)n * 128 + sub * 8);
  *(float4*)&x[4] = *(const float4*)(H + (size_t)n * 128 + sub * 8 + 4);
  float gx[8], gh[8];
  *(float4*)&gx[0] = *(const float4*)(GW + sub * 8);
  *(float4*)&gx[4] = *(const float4*)(GW + sub * 8 + 4);
  *(float4*)&gh[0] = *(const float4*)(GW + 128 + sub * 8);
  *(float4*)&gh[4] = *(const float4*)(GW + 128 + sub * 8 + 4);
  float g = 0.f;
  #pragma unroll
  for (int q = 0; q < 8; ++q) g += x[q] * gx[q] + acc[q] * gh[q];
  #pragma unroll
  for (int o = 8; o; o >>= 1) g += __shfl_xor(g, o, 64);
  g += GB[0];
  float z = 1.f / (1.f + __expf(-g));
  #pragma unroll
  for (int q = 0; q < 8; ++q) x[q] = z * x[q] + (1.f - z) * acc[q];
  *(float4*)(H + (size_t)n * 128 + sub * 8)     = *(float4*)&x[0];
  *(float4*)(H + (size_t)n * 128 + sub * 8 + 4) = *(float4*)&x[4];
  uint4 hw;
  hw.x = f2bf2(x[0], x[1]); hw.y = f2bf2(x[2], x[3]);
  hw.z = f2bf2(x[4], x[5]); hw.w = f2bf2(x[6], x[7]);
  *(uint4*)(Hh + (size_t)n * 64 + sub * 4) = hw;
}

// ---------------- final inter-graph edges: 16 lanes per edge, 1-deep pipeline ----------------
__global__ __launch_bounds__(256) void k_edges(
    const int* __restrict__ EI,
    const float4* __restrict__ PRAD, const uint* __restrict__ MB,
    const uint* __restrict__ Pd, const uint* __restrict__ Qd,
    const uint* __restrict__ Pe, const uint* __restrict__ Qe,
    const float* __restrict__ w2d, const float* __restrict__ b2d,
    const float* __restrict__ w2e, const float* __restrict__ b2e,
    const float* __restrict__ hbc, const float* __restrict__ hpc,
    float* __restrict__ geng, float* __restrict__ outdv){
  __shared__ float eg[NG * 4];
  int tid = threadIdx.x;
  for (int i = tid; i < NG * 4; i += 256) eg[i] = 0.f;
  __syncthreads();
  int sub = tid & 15;
  int gid = blockIdx.x * 16 + (tid >> 4);
  int ngrp = gridDim.x * 16;
  float wdv[8], wev[8];
  *(float4*)&wdv[0] = *(const float4*)(w2d + sub * 8);
  *(float4*)&wdv[4] = *(const float4*)(w2d + sub * 8 + 4);
  *(float4*)&wev[0] = *(const float4*)(w2e + sub * 8);
  *(float4*)&wev[4] = *(const float4*)(w2e + sub * 8 + 4);
  float bd = b2d[0], be = b2e[0];
  float minhb = -hbc[0] * hbc[0], minhp = -hpc[0] * hpc[0];

  int e = gid;
  uint4 pd0 = {}, qd0 = {}, pe0 = {}, qe0 = {};
  float4 pri0 = {}, prj0 = {};
  uint mbi0 = 0, mbj0 = 0;
  int i1 = 0, j1 = 0;
  if (e < EIN){
    int i0 = EI[e], j0 = EI[EIN + e];
    pd0 = *(const uint4*)(Pd + (size_t)i0 * 64 + sub * 4);
    qd0 = *(const uint4*)(Qd + (size_t)j0 * 64 + sub * 4);
    pe0 = *(const uint4*)(Pe + (size_t)i0 * 64 + sub * 4);
    qe0 = *(const uint4*)(Qe + (size_t)j0 * 64 + sub * 4);
    pri0 = PRAD[i0]; prj0 = PRAD[j0]; mbi0 = MB[i0]; mbj0 = MB[j0];
  }
  if (e + ngrp < EIN){ i1 = EI[e + ngrp]; j1 = EI[EIN + e + ngrp]; }

  for (; e < EIN; e += ngrp){
    uint4 pd1 = {}, qd1 = {}, pe1 = {}, qe1 = {};
    float4 pri1 = {}, prj1 = {};
    uint mbi1 = 0, mbj1 = 0;
    int i2 = 0, j2 = 0;
    if (e + ngrp < EIN){
      pd1 = *(const uint4*)(Pd + (size_t)i1 * 64 + sub * 4);
      qd1 = *(const uint4*)(Qd + (size_t)j1 * 64 + sub * 4);
      pe1 = *(const uint4*)(Pe + (size_t)i1 * 64 + sub * 4);
      qe1 = *(const uint4*)(Qe + (size_t)j1 * 64 + sub * 4);
      pri1 = PRAD[i1]; prj1 = PRAD[j1]; mbi1 = MB[i1]; mbj1 = MB[j1];
    }
    if (e + 2 * ngrp < EIN){ i2 = EI[e + 2 * ngrp]; j2 = EI[EIN + e + 2 * ngrp]; }

    float pdf[8], qdf[8], pef[8], qef[8];
    decode8(pd0, pdf); decode8(qd0, qdf); decode8(pe0, pef); decode8(qe0, qef);
    float sd = 0.f, se = 0.f;
    #pragma unroll
    for (int q = 0; q < 8; ++q){
      sd += fmaxf(pdf[q] + qdf[q], 0.f) * wdv[q];
      se += fmaxf(pef[q] + qef[q], 0.f) * wev[q];
    }
    #pragma unroll
    for (int o = 8; o; o >>= 1){
      sd += __shfl_xor(sd, o, 64);
      se += __shfl_xor(se, o, 64);
    }
    sd += bd; se += be;
    float dx = pri0.x - prj0.x, dy = pri0.y - prj0.y, dz = pri0.z - prj0.z;
    float D = sqrtf(dx * dx + dy * dy + dz * dz + 1e-10f);
    float rmask = (D >= 0.5f && D <= 5.0f) ? 1.f : 0.f;
    float dvdw = tanhf(sd) * DEV_VDW * rmask;
    float eps = (1.f / (1.f + __expf(-se))) * (EPS_HI_ - EPS_LO_) + EPS_LO_;
    float R = pri0.w + prj0.w + dvdw;
    float dr = fmaxf(D / R, 0.5f);
    float nn2 = (dr < 1.f) ? 10.f : 6.f;
    float tp = __expf(-nn2 * __logf(dr));
    float ev = eps * (tp * tp - 2.f * tp);
    float dmr = D - R;
    float f1 = fminf(fmaxf(dmr * (-1.f / 0.7f), 0.f), 1.f);
    float f3 = fminf(fmaxf(1.5f - dmr, 0.f), 1.f);
    bool metI = mbi0 & 1, metJ = mbj0 & 1;
    bool donI = mbi0 & 2, donJ = mbj0 & 2;
    bool accI = mbi0 & 4, accJ = mbj0 & 4;
    bool hyI  = mbi0 & 8, hyJ  = mbj0 & 8;
    bool nm = !(metI || metJ);
    float E0 = nm ? ev * rmask : 0.f;
    float E1 = (((donI && accJ) || (accI && donJ)) && nm) ? minhb * f1 * rmask : 0.f;
    float E2 = ((metI && accJ) || (accI && metJ)) ? minhb * f1 * rmask : 0.f;
    float E3 = (hyI && hyJ && nm) ? minhp * f3 * rmask : 0.f;
    if (sub == 0){
      outdv[e] = dvdw;
      int g = (int)(mbi0 >> 8) * 4;
      atomicAdd(&eg[g + 0], E0);
      atomicAdd(&eg[g + 1], E1);
      atomicAdd(&eg[g + 2], E2);
      atomicAdd(&eg[g + 3], E3);
    }
    pd0 = pd1; qd0 = qd1; pe0 = pe1; qe0 = qe1;
    pri0 = pri1; prj0 = prj1; mbi0 = mbi1; mbj0 = mbj1;
    i1 = i2; j1 = j2;
  }
  __syncthreads();
  float* part = geng + (size_t)(blockIdx.x & 7) * (NG * 4);
  for (int i2 = tid; i2 < NG * 4; i2 += 256) atomicAdd(&part[i2], eg[i2]);
}

__global__ void k_final(const float* __restrict__ geng, const float* __restrict__ rotor,
                        const float* __restrict__ rc, float* __restrict__ out){
  int t = blockIdx.x * blockDim.x + threadIdx.x;
  if (t < NG * 4){
    int g = t >> 2;
    float s = 0.f;
    #pragma unroll
    for (int p = 0; p < 8; ++p) s += geng[p * NG * 4 + t];
    float pen = 1.f + rc[0] * rc[0] * rotor[g];
    out[t] = s / pen;
  }
}

extern "C" void kernel_launch(void* const* d_in, const int* in_sizes, int n_in,
                              void* d_out, int out_size, void* d_ws, size_t ws_size,
                              hipStream_t stream){
  (void)in_sizes; (void)n_in; (void)out_size; (void)ws_size;
  const float* X    = (const float*)d_in[0];
  const float* POS  = (const float*)d_in[1];
  const float* RAD  = (const float*)d_in[2];
  const float* ROT  = (const float*)d_in[3];
  const int* EIa    = (const int*)d_in[4];
  const int* EIc    = (const int*)d_in[5];
  const int* EIi    = (const int*)d_in[6];
  const int* BATCH  = (const int*)d_in[7];
  const int* Mmet = (const int*)d_in[8];
  const int* Mdon = (const int*)d_in[9];
  const int* Macc = (const int*)d_in[10];
  const int* Mhyd = (const int*)d_in[11];
  const float* embW  = (const float*)d_in[12];
  const float* gatW  = (const float*)d_in[13];
  const float* gatWb = (const float*)d_in[14];
  const float* gatA  = (const float*)d_in[15];
  const float* gatGw = (const float*)d_in[16];
  const float* gatGb = (const float*)d_in[17];
  const float* intW  = (const float*)d_in[18];
  const float* intWb = (const float*)d_in[19];
  const float* intGw = (const float*)d_in[20];
  const float* intGb = (const float*)d_in[21];
  const float* ew1 = (const float*)d_in[22];
  const float* eb1 = (const float*)d_in[23];
  const float* ew2 = (const float*)d_in[24];
  const float* eb2 = (const float*)d_in[25];
  const float* dw1 = (const float*)d_in[26];
  const float* db1 = (const float*)d_in[27];
  const float* dw2 = (const float*)d_in[28];
  const float* db2 = (const float*)d_in[29];
  const float* hbc = (const float*)d_in[30];
  const float* hpc = (const float*)d_in[31];
  const float* rcc = (const float*)d_in[32];
  float* out = (float*)d_out;

  char* w = (char*)d_ws;
  float* H   = (float*)w; w += (size_t)NN * 128 * 4;   // 25.6 MB
  uint* Hh   = (uint*)w;  w += (size_t)NN * 64 * 4;    // 12.8 MB bf16 shadow of H
  uint* BAh  = (uint*)w;  w += (size_t)NN * 64 * 4;    // 12.8 MB
  uint* BBh  = (uint*)w;  w += (size_t)NN * 64 * 4;    // 12.8 MB
  uint* Peh  = (uint*)w;  w += (size_t)NN * 64 * 4;    // 12.8 MB
  uint* Qeh  = (uint*)w;  w += (size_t)NN * 64 * 4;    // 12.8 MB
  uint* WT   = (uint*)w;  w += (size_t)13 * 8192 * 4;  // 416 KB transposed bf16 weights
  float* BIASB = (float*)w; w += 640 * 4;              // bias4[512] + zeros128
  float4* PRAD = (float4*)w; w += (size_t)NN * 16;
  uint* MBb  = (uint*)w;  w += (size_t)NN * 4;
  float* GENG = (float*)w; w += (size_t)8 * 512 * 4;   // 8-way partials
  int* cntA = (int*)w; w += (size_t)NN * 4;
  int* offA = (int*)w; w += (size_t)(NN + 1) * 4;
  int* curA = (int*)w; w += (size_t)NN * 4;
  int* srcA = (int*)w; w += (size_t)EA * 4;
  int* cntC = (int*)w; w += (size_t)NN * 4;
  int* offC = (int*)w; w += (size_t)(NN + 1) * 4;
  int* curC = (int*)w; w += (size_t)NN * 4;
  int* srcC = (int*)w; w += (size_t)EC * 4;
  uint* Th  = BAh;   // aliases: phases are sequential
  uint* Pdh = BAh;   // tail outputs: BAh,BBh,Peh,Qeh are contiguous
  uint* Qdh = BBh;
  const float* zeros128 = BIASB + 512;

  hipMemsetAsync(cntA, 0, (size_t)NN * 4, stream);
  hipMemsetAsync(cntC, 0, (size_t)NN * 4, stream);
  hipMemsetAsync(GENG, 0, (size_t)8 * 512 * 4, stream);

  k_count<<<1024, 256, 0, stream>>>(EIa + EA, EA, cntA);
  k_scan<<<1, 1024, 0, stream>>>(cntA, NN, offA, curA);
  k_place<<<1024, 256, 0, stream>>>(EIa, EIa + EA, EA, curA, srcA);
  k_count<<<1024, 256, 0, stream>>>(EIc + EC, EC, cntC);
  k_scan<<<1, 1024, 0, stream>>>(cntC, NN, offC, curC);
  k_place<<<1024, 256, 0, stream>>>(EIc, EIc + EC, EC, curC, srcC);

  k_prepw<<<14, 256, 0, stream>>>(gatW, gatA, intW, dw1, ew1, db1, eb1, WT, BIASB);
  k_nodeinfo<<<(NN + 255) / 256, 256, 0, stream>>>(POS, RAD, Mmet, Mdon, Macc, Mhyd, BATCH, PRAD, MBb);
  k_embed<<<2048, 128, 0, stream>>>(X, embW, H, Hh);

  int gg = (NN + 127) / 128;
  int nodeGrid = (NN + 15) / 16;
  for (int l = 0; l < 3; ++l){
    k_gemm_mfma<false><<<dim3(gg, 1), 256, 0, stream>>>(Hh,  WT + (size_t)l * 8192,       gatWb + l * 128, BAh, 0, NN);
    k_gemm_mfma<false><<<dim3(gg, 1), 256, 0, stream>>>(BAh, WT + (size_t)(3 + l) * 8192, zeros128,        BBh, 0, NN);
    k_gat<<<nodeGrid, 256, 0, stream>>>(H, Hh, BAh, BBh, offA, srcA, gatGw + l * 256, gatGb + l);
  }
  for (int l = 0; l < 3; ++l){
    k_gemm_mfma<true><<<dim3(gg, 1), 256, 0, stream>>>(Hh, WT + (size_t)(6 + l) * 8192, intWb + l * 128, Th, 0, NN);
    k_inter<<<nodeGrid, 256, 0, stream>>>(H, Hh, Th, offC, srcC, intGw + l * 256, intGb + l);
  }
  // tail: 4 GEMMs fused via blockIdx.y -> Pd,Qd,Pe,Qe (contiguous outputs from BAh)
  k_gemm_mfma<false><<<dim3(gg, 4), 256, 0, stream>>>(Hh, WT + (size_t)9 * 8192, BIASB, BAh, (size_t)NN * 64, NN);

  k_edges<<<2048, 256, 0, stream>>>(EIi, PRAD, MBb, Pdh, Qdh, Peh, Qeh,
                                    dw2, db2, ew2, eb2, hbc, hpc,
                                    GENG, out + 512);
  k_final<<<2, 256, 0, stream>>>(GENG, ROT, rcc, out);
}